// Round 8
// baseline (87.386 us; speedup 1.0000x reference)
//
#include <hip/hip_runtime.h>
#include <hip/hip_bf16.h>

typedef __bf16 bf16_t;
typedef bf16_t bf16x8 __attribute__((ext_vector_type(8)));
typedef float f32x4 __attribute__((ext_vector_type(4)));
typedef float f32x16 __attribute__((ext_vector_type(16)));

#define NHEADS 16
#define DFEAT 64
#define DCOORD 8
#define SEQ 2048
#define KVBLK 64
#define NT (SEQ / KVBLK)
#define QBLK 128                       // 2 waves x 2 q-sets x 32 q-rows
#define KCOLS 96                       // K' cols (bf16): 64 feat + 8 coord + 24 zero
#define KROWB (KCOLS * 2)              // 192 B row stride
#define KTILEB (KVBLK * KROWB)         // 12288 B per K tile
#define VTILEB (KVBLK * DFEAT * 2)     // 8192 B per V^T tile image
#define VTILE_ELEMS (KVBLK * DFEAT)

#define KP_BYTES ((size_t)32 * NT * KTILEB)   // 12,582,912
#define VT_BYTES ((size_t)32 * NT * VTILEB)   //  8,388,608

union Bf8 { bf16x8 v; __hip_bfloat16 e[8]; };
union U4  { unsigned u[4]; bf16x8 v; };

static __device__ inline unsigned pack2(float a, float b) {
    union { __hip_bfloat16 h[2]; unsigned u; } x;
    x.h[0] = __float2bfloat16(a); x.h[1] = __float2bfloat16(b);
    return x.u;
}

// ---------------------------------------------------------------------------
// Merged pre-pass: blocks [0,1024) pack K' tiles, [1024,2048) pack V^T tiles.
// K' (verified r4/r5): byte = row*192 + (off ^ key); feat region key=(row&7)<<4,
//   coord region key=(row&3)<<4. cols 0..63 kf, 64..71 kc, rest 0.
// V^T (verified r5): s-columns permuted by bit2<->bit3 swap (lane-local P
//   packing); byte = (d*128 + slot*2) ^ ((d&7)<<4).
// ---------------------------------------------------------------------------
__global__ __launch_bounds__(256)
void pack_kv(const float* __restrict__ kf, const float* __restrict__ kc,
             const float* __restrict__ v,
             char* __restrict__ kp, char* __restrict__ vt)
{
    __shared__ __align__(16) char tile[KTILEB];   // 12288 B (V uses 8192 of it)
    const int bid = blockIdx.x;
    const int tid = threadIdx.x;

    if (bid < 1024) {
        // ---------------- K' pack ----------------
        const int blk = bid;               // [bh][t]
        const int t  = blk & (NT - 1);
        const int bh = blk >> 5;
        const int b = bh >> 4, h = bh & 15;
        #pragma unroll
        for (int it = 0; it < 2; ++it) {
            const int c = tid + it * 256;      // 384 chunks of 16 elems
            if (c < 384) {
                const int row = c / 6, cc = c - row * 6;
                const int s = t * KVBLK + row;
                float vv[16];
                if (cc < 4) {
                    const float* p = kf + ((long)b * SEQ + s) * (NHEADS * DFEAT) + h * DFEAT + cc * 16;
                    #pragma unroll
                    for (int i = 0; i < 4; ++i) {
                        float4 f = ((const float4*)p)[i];
                        vv[4*i+0]=f.x; vv[4*i+1]=f.y; vv[4*i+2]=f.z; vv[4*i+3]=f.w;
                    }
                } else if (cc == 4) {
                    const float* p = kc + ((long)b * SEQ + s) * (NHEADS * DCOORD) + h * DCOORD;
                    float4 f0 = ((const float4*)p)[0];
                    float4 f1 = ((const float4*)p)[1];
                    vv[0]=f0.x; vv[1]=f0.y; vv[2]=f0.z; vv[3]=f0.w;
                    vv[4]=f1.x; vv[5]=f1.y; vv[6]=f1.z; vv[7]=f1.w;
                    #pragma unroll
                    for (int i = 8; i < 16; ++i) vv[i] = 0.f;
                } else {
                    #pragma unroll
                    for (int i = 0; i < 16; ++i) vv[i] = 0.f;
                }
                Bf8 w0, w1;
                #pragma unroll
                for (int i = 0; i < 8; ++i) {
                    w0.e[i] = __float2bfloat16(vv[i]);
                    w1.e[i] = __float2bfloat16(vv[i + 8]);
                }
                const int key  = ((cc < 4) ? (row & 7) : (row & 3)) << 4;
                const int base = cc * 32;
                *(bf16x8*)&tile[row * KROWB + ((base)      ^ key)] = w0.v;
                *(bf16x8*)&tile[row * KROWB + ((base + 16) ^ key)] = w1.v;
            }
        }
        __syncthreads();
        const bf16x8* ti = (const bf16x8*)tile;
        bf16x8* o = (bf16x8*)(kp + (long)blk * KTILEB);
        #pragma unroll
        for (int j = 0; j < 3; ++j) o[tid + 256 * j] = ti[tid + 256 * j];   // 768 x 16B
    } else {
        // ---------------- V^T pack ----------------
        const int blk = bid - 1024;        // [bh][t]
        const int t  = blk & (NT - 1);
        const int bh = blk >> 5;
        const int b = bh >> 4, h = bh & 15;
        __hip_bfloat16* vtile = (__hip_bfloat16*)tile;
        const int s = tid >> 2, c = tid & 3;
        const int slot = (s & ~12) | ((s & 4) << 1) | ((s & 8) >> 1);  // swap bits 2,3
        const float* src = v + ((long)b * SEQ + t * KVBLK + s) * (NHEADS * DFEAT) + h * DFEAT;
        #pragma unroll
        for (int c4 = 0; c4 < 4; ++c4) {
            float4 f = ((const float4*)src)[c4 * 4 + c];
            float vals[4] = {f.x, f.y, f.z, f.w};
            #pragma unroll
            for (int ii = 0; ii < 4; ++ii) {
                const int dd = c4 * 16 + c * 4 + ii;
                const int byte = (dd * 128 + slot * 2) ^ ((dd & 7) << 4);
                vtile[byte >> 1] = __float2bfloat16(vals[ii]);
            }
        }
        __syncthreads();
        const bf16x8* ti = (const bf16x8*)vtile;
        bf16x8* o = (bf16x8*)(vt + (long)blk * (long)VTILEB);
        o[tid]       = ti[tid];
        o[tid + 256] = ti[tid + 256];
    }
}

// ---------------------------------------------------------------------------
// Main kernel v8: q-register-blocked (2 q-sets/wave) in 128-thread blocks.
// Each K/V LDS fragment read ONCE feeds TWO MFMAs (v7's reuse) while 4
// blocks/CU keep 2 waves/SIMD resident (v5's TLP). Counted-vmcnt pipeline:
// 10 loads/wave/stage, vmcnt(10) holds next tile's loads in flight.
// ---------------------------------------------------------------------------
__global__ __launch_bounds__(128, 2)
void stfa_v8(const float* __restrict__ qf, const float* __restrict__ qc,
             const float* __restrict__ alpha,
             const char* __restrict__ kp, const char* __restrict__ vt,
             float* __restrict__ out)
{
    __shared__ __align__(16) char Kbuf[2][KTILEB];   // 24576 B
    __shared__ __align__(16) char Vbuf[2][VTILEB];   // 16384 B

    const int tid  = threadIdx.x;
    const int wave = tid >> 6;    // 0..1
    const int lane = tid & 63;
    const int lq   = lane & 31;   // q column within a q-set
    const int hi   = lane >> 5;   // half-wave: k-slot select

    const int dd    = blockIdx.x;     // [qtile(4b)][bh(5b)]: same-bh -> same XCD
    const int bh    = dd & 31;
    const int qtile = dd >> 5;        // 0..15
    const int b = bh >> 4, h = bh & 15;

    const float a_h      = alpha[h];
    const float LOG2E    = 1.4426950408889634f;
    const float qf_scale = 0.125f * LOG2E;
    const float qc_scale = a_h * 0.35355339059327373f * LOG2E;

    const char* kp_bh = kp + (long)bh * NT * KTILEB;
    const char* vt_bh = vt + (long)bh * NT * VTILEB;

    auto stage = [&](int bb, int t) {
        const char* kg = kp_bh + (long)t * KTILEB;
        const char* vg = vt_bh + (long)t * VTILEB;
        char* kl = &Kbuf[bb][0];
        char* vl = &Vbuf[bb][0];
        #pragma unroll
        for (int j = 0; j < 6; ++j) {            // 12 x 1KB K chunks over 2 waves
            const int i = wave + 2 * j;
            __builtin_amdgcn_global_load_lds(
                (const __attribute__((address_space(1))) void*)(kg + i * 1024 + lane * 16),
                (__attribute__((address_space(3))) void*)(kl + i * 1024), 16, 0, 0);
        }
        #pragma unroll
        for (int j = 0; j < 4; ++j) {            // 8 x 1KB V chunks over 2 waves
            const int i = wave + 2 * j;
            __builtin_amdgcn_global_load_lds(
                (const __attribute__((address_space(1))) void*)(vg + i * 1024 + lane * 16),
                (__attribute__((address_space(3))) void*)(vl + i * 1024), 16, 0, 0);
        }
    };

    stage(0, 0);

    // ---- Q' fragments for both q-sets (A: wave*64+lq, B: +32) ----
    const int qrowA = qtile * QBLK + wave * 64 + lq;
    const int qrowB = qrowA + 32;

    bf16x8 qfragA[5], qfragB[5];
    #pragma unroll
    for (int set = 0; set < 2; ++set) {
        const int qrow = set ? qrowB : qrowA;
        const float* qfp = qf + ((long)b * SEQ + qrow) * (NHEADS * DFEAT) + h * DFEAT;
        const float* qcp = qc + ((long)b * SEQ + qrow) * (NHEADS * DCOORD) + h * DCOORD;
        #pragma unroll
        for (int ks = 0; ks < 4; ++ks) {
            const float* p = qfp + ks * 16 + hi * 8;
            float4 f0 = *(const float4*)p;
            float4 f1 = *(const float4*)(p + 4);
            Bf8 q;
            q.e[0] = __float2bfloat16(f0.x * qf_scale); q.e[1] = __float2bfloat16(f0.y * qf_scale);
            q.e[2] = __float2bfloat16(f0.z * qf_scale); q.e[3] = __float2bfloat16(f0.w * qf_scale);
            q.e[4] = __float2bfloat16(f1.x * qf_scale); q.e[5] = __float2bfloat16(f1.y * qf_scale);
            q.e[6] = __float2bfloat16(f1.z * qf_scale); q.e[7] = __float2bfloat16(f1.w * qf_scale);
            if (set) qfragB[ks] = q.v; else qfragA[ks] = q.v;
        }
        Bf8 q;
        #pragma unroll
        for (int i = 0; i < 8; ++i) q.e[i] = __float2bfloat16(0.0f);
        if (hi == 0) {   // k = 64..71 = coord; k = 72..79 stays zero
            float4 c0 = *(const float4*)qcp;
            float4 c1 = *(const float4*)(qcp + 4);
            q.e[0] = __float2bfloat16(c0.x * qc_scale); q.e[1] = __float2bfloat16(c0.y * qc_scale);
            q.e[2] = __float2bfloat16(c0.z * qc_scale); q.e[3] = __float2bfloat16(c0.w * qc_scale);
            q.e[4] = __float2bfloat16(c1.x * qc_scale); q.e[5] = __float2bfloat16(c1.y * qc_scale);
            q.e[6] = __float2bfloat16(c1.z * qc_scale); q.e[7] = __float2bfloat16(c1.w * qc_scale);
        }
        if (set) qfragB[4] = q.v; else qfragA[4] = q.v;
    }

    f32x16 oaccA[2], oaccB[2];
    #pragma unroll
    for (int dt = 0; dt < 2; ++dt)
        #pragma unroll
        for (int r = 0; r < 16; ++r) { oaccA[dt][r] = 0.f; oaccB[dt][r] = 0.f; }
    float lA = 0.f, lB = 0.f;

    asm volatile("s_waitcnt vmcnt(0)" ::: "memory");
    __builtin_amdgcn_s_barrier();     // tile 0 resident

    int bb = 0;
    for (int t = 0; t < NT; ++t) {
        if (t + 1 < NT) {
            stage(bb ^ 1, t + 1);                               // +10 loads/wave in flight
            asm volatile("s_waitcnt vmcnt(10)" ::: "memory");   // tile t landed; t+1 stays out
        } else {
            asm volatile("s_waitcnt vmcnt(0)" ::: "memory");
        }
        __builtin_amdgcn_s_barrier();                  // tile t visible to both waves
        __builtin_amdgcn_sched_barrier(0);

        // ---- QK'^T: 2 s-tiles x 5 k-steps; each kfrag feeds both q-sets ----
        f32x16 saccA[2], saccB[2];
        #pragma unroll
        for (int st = 0; st < 2; ++st)
            #pragma unroll
            for (int r = 0; r < 16; ++r) { saccA[st][r] = 0.f; saccB[st][r] = 0.f; }
        __builtin_amdgcn_s_setprio(1);
        #pragma unroll
        for (int st = 0; st < 2; ++st) {
            const int row = st * 32 + lq;
            #pragma unroll
            for (int ks = 0; ks < 5; ++ks) {
                const int off = ks * 32 + hi * 16;
                const int key = ((ks < 4) ? (lq & 7) : (lq & 3)) << 4;
                bf16x8 kfrag = *(const bf16x8*)&Kbuf[bb][row * KROWB + (off ^ key)];
                saccA[st] = __builtin_amdgcn_mfma_f32_32x32x16_bf16(kfrag, qfragA[ks], saccA[st], 0, 0, 0);
                saccB[st] = __builtin_amdgcn_mfma_f32_32x32x16_bf16(kfrag, qfragB[ks], saccB[st], 0, 0, 0);
            }
        }
        __builtin_amdgcn_s_setprio(0);

        // ---- P = exp2(S); lane-local pack (V column permutation) ----
        bf16x8 pfragA[4], pfragB[4];
        #pragma unroll
        for (int set = 0; set < 2; ++set) {
            float lsum = 0.f;
            #pragma unroll
            for (int T = 0; T < 2; ++T) {
                float p[16];
                #pragma unroll
                for (int r = 0; r < 16; ++r)
                    p[r] = __builtin_amdgcn_exp2f(set ? saccB[T][r] : saccA[T][r]);
                U4 fa, fb;
                #pragma unroll
                for (int i = 0; i < 4; ++i) {
                    fa.u[i] = pack2(p[2 * i],     p[2 * i + 1]);
                    fb.u[i] = pack2(p[2 * i + 8], p[2 * i + 9]);
                }
                if (set) { pfragB[2 * T] = fa.v; pfragB[2 * T + 1] = fb.v; }
                else     { pfragA[2 * T] = fa.v; pfragA[2 * T + 1] = fb.v; }
                float s8[8];
                #pragma unroll
                for (int r = 0; r < 8; ++r) s8[r] = p[r] + p[r + 8];
                float s4[4];
                #pragma unroll
                for (int r = 0; r < 4; ++r) s4[r] = s8[r] + s8[r + 4];
                lsum += (s4[0] + s4[1]) + (s4[2] + s4[3]);
            }
            if (set) lB += lsum; else lA += lsum;
        }

        // ---- PV: 2 d-tiles x 4 k-steps; each vfrag feeds both q-sets ----
        __builtin_amdgcn_s_setprio(1);
        #pragma unroll
        for (int dt = 0; dt < 2; ++dt) {
            const int row = dt * 32 + lq;
            #pragma unroll
            for (int ks = 0; ks < 4; ++ks) {
                bf16x8 vfrag = *(const bf16x8*)&Vbuf[bb][row * 128 +
                                   ((ks * 32 + hi * 16) ^ ((lq & 7) << 4))];
                oaccA[dt] = __builtin_amdgcn_mfma_f32_32x32x16_bf16(vfrag, pfragA[ks], oaccA[dt], 0, 0, 0);
                oaccB[dt] = __builtin_amdgcn_mfma_f32_32x32x16_bf16(vfrag, pfragB[ks], oaccB[dt], 0, 0, 0);
            }
        }
        __builtin_amdgcn_s_setprio(0);

        __builtin_amdgcn_s_barrier();   // both waves done reading buf bb
        bb ^= 1;
    }

    // ---- l reduction + epilogue per q-set ----
    const float lAt = lA + __shfl_xor(lA, 32);
    const float lBt = lB + __shfl_xor(lB, 32);
    const float invlA = 1.0f / lAt;
    const float invlB = 1.0f / lBt;

    #pragma unroll
    for (int set = 0; set < 2; ++set) {
        const int qrow = set ? qrowB : qrowA;
        const float invl = set ? invlB : invlA;
        float* ob = out + ((long)b * SEQ + qrow) * (NHEADS * DFEAT) + h * DFEAT;
        #pragma unroll
        for (int dt = 0; dt < 2; ++dt) {
            #pragma unroll
            for (int g = 0; g < 4; ++g) {
                const int d0 = dt * 32 + g * 8 + hi * 4;
                float4 o;
                const f32x16& oa = set ? oaccB[dt] : oaccA[dt];
                o.x = oa[4 * g + 0] * invl;
                o.y = oa[4 * g + 1] * invl;
                o.z = oa[4 * g + 2] * invl;
                o.w = oa[4 * g + 3] * invl;
                *(float4*)(ob + d0) = o;
            }
        }
    }
}

// ---------------------------------------------------------------------------
// v1 fallback (round-1 kernel, proven) if ws is too small for pack buffers.
// ---------------------------------------------------------------------------
__global__ __launch_bounds__(256)
void stfa_v1(const float* __restrict__ qf, const float* __restrict__ kf,
             const float* __restrict__ qc, const float* __restrict__ kc,
             const float* __restrict__ vv, const float* __restrict__ alpha,
             float* __restrict__ out)
{
    __shared__ __align__(16) __hip_bfloat16 Klds[64 * 104];
    __shared__ __align__(16) __hip_bfloat16 Vlds[64 * 72];
    __shared__ __align__(16) __hip_bfloat16 Plds[4 * 16 * 72];

    const int tid  = threadIdx.x;
    const int wave = tid >> 6;
    const int lane = tid & 63;
    const int lr   = lane & 15;
    const int lg   = lane >> 4;

    const int blk   = blockIdx.x;
    const int qtile = blk & 31;
    const int h     = (blk >> 5) & 15;
    const int b     = blk >> 9;

    for (int i = tid; i < 64 * 104; i += 256) Klds[i] = __float2bfloat16(0.0f);

    const float a_h      = alpha[h];
    const float LOG2E    = 1.4426950408889634f;
    const float qf_scale = 0.125f * LOG2E;
    const float qc_scale = a_h * 0.35355339059327373f * LOG2E;

    const int qrow = qtile * 64 + wave * 16 + lr;
    const float* qf_p = qf + ((long)b * SEQ + qrow) * 1024 + h * 64;
    const float* qc_p = qc + ((long)b * SEQ + qrow) * 128 + h * 8;

    bf16x8 qfrag[3];
    #pragma unroll
    for (int st = 0; st < 2; ++st) {
        const float* p = qf_p + st * 32 + lg * 8;
        float4 f0 = *(const float4*)p;
        float4 f1 = *(const float4*)(p + 4);
        Bf8 q;
        q.e[0] = __float2bfloat16(f0.x * qf_scale); q.e[1] = __float2bfloat16(f0.y * qf_scale);
        q.e[2] = __float2bfloat16(f0.z * qf_scale); q.e[3] = __float2bfloat16(f0.w * qf_scale);
        q.e[4] = __float2bfloat16(f1.x * qf_scale); q.e[5] = __float2bfloat16(f1.y * qf_scale);
        q.e[6] = __float2bfloat16(f1.z * qf_scale); q.e[7] = __float2bfloat16(f1.w * qf_scale);
        qfrag[st] = q.v;
    }
    {
        Bf8 q;
        #pragma unroll
        for (int i = 0; i < 8; ++i) q.e[i] = __float2bfloat16(0.0f);
        if (lg == 0) {
            float4 c0 = *(const float4*)qc_p;
            float4 c1 = *(const float4*)(qc_p + 4);
            q.e[0] = __float2bfloat16(c0.x * qc_scale); q.e[1] = __float2bfloat16(c0.y * qc_scale);
            q.e[2] = __float2bfloat16(c0.z * qc_scale); q.e[3] = __float2bfloat16(c0.w * qc_scale);
            q.e[4] = __float2bfloat16(c1.x * qc_scale); q.e[5] = __float2bfloat16(c1.y * qc_scale);
            q.e[6] = __float2bfloat16(c1.z * qc_scale); q.e[7] = __float2bfloat16(c1.w * qc_scale);
        }
        qfrag[2] = q.v;
    }

    const float* kf_b = kf + (long)b * SEQ * 1024 + h * 64;
    const float* kc_b = kc + (long)b * SEQ * 128 + h * 8;
    const float* v_b  = vv + (long)b * SEQ * 1024 + h * 64;

    f32x4 oacc[4];
    #pragma unroll
    for (int ct = 0; ct < 4; ++ct) { oacc[ct][0]=0.f; oacc[ct][1]=0.f; oacc[ct][2]=0.f; oacc[ct][3]=0.f; }
    float m_r[4], l_r[4];
    #pragma unroll
    for (int j = 0; j < 4; ++j) { m_r[j] = -3.0e38f; l_r[j] = 0.f; }

    __syncthreads();

    for (int s0 = 0; s0 < SEQ; s0 += 64) {
        {
            const int srow = tid >> 2, ch = tid & 3;
            const float* p = kf_b + (long)(s0 + srow) * 1024 + ch * 16;
            float4 f0 = ((const float4*)p)[0];
            float4 f1 = ((const float4*)p)[1];
            float4 f2 = ((const float4*)p)[2];
            float4 f3 = ((const float4*)p)[3];
            Bf8 w0, w1;
            w0.e[0]=__float2bfloat16(f0.x); w0.e[1]=__float2bfloat16(f0.y);
            w0.e[2]=__float2bfloat16(f0.z); w0.e[3]=__float2bfloat16(f0.w);
            w0.e[4]=__float2bfloat16(f1.x); w0.e[5]=__float2bfloat16(f1.y);
            w0.e[6]=__float2bfloat16(f1.z); w0.e[7]=__float2bfloat16(f1.w);
            w1.e[0]=__float2bfloat16(f2.x); w1.e[1]=__float2bfloat16(f2.y);
            w1.e[2]=__float2bfloat16(f2.z); w1.e[3]=__float2bfloat16(f2.w);
            w1.e[4]=__float2bfloat16(f3.x); w1.e[5]=__float2bfloat16(f3.y);
            w1.e[6]=__float2bfloat16(f3.z); w1.e[7]=__float2bfloat16(f3.w);
            *(bf16x8*)&Klds[srow * 104 + ch * 16]     = w0.v;
            *(bf16x8*)&Klds[srow * 104 + ch * 16 + 8] = w1.v;
        }
        {
            const int srow = tid >> 2, cp = (tid & 3) * 2;
            const float* p = kc_b + (long)(s0 + srow) * 128 + cp;
            float2 c = *(const float2*)p;
            Klds[srow * 104 + 64 + cp]     = __float2bfloat16(c.x);
            Klds[srow * 104 + 64 + cp + 1] = __float2bfloat16(c.y);
        }
        {
            const int srow = tid & 63, d0 = (tid >> 6) * 16;
            const float* p = v_b + (long)(s0 + srow) * 1024 + d0;
            #pragma unroll
            for (int c4 = 0; c4 < 4; ++c4) {
                float4 f = ((const float4*)p)[c4];
                Vlds[(d0 + c4 * 4 + 0) * 72 + srow] = __float2bfloat16(f.x);
                Vlds[(d0 + c4 * 4 + 1) * 72 + srow] = __float2bfloat16(f.y);
                Vlds[(d0 + c4 * 4 + 2) * 72 + srow] = __float2bfloat16(f.z);
                Vlds[(d0 + c4 * 4 + 3) * 72 + srow] = __float2bfloat16(f.w);
            }
        }
        __syncthreads();

        f32x4 sacc[4];
        #pragma unroll
        for (int ct = 0; ct < 4; ++ct) { sacc[ct][0]=0.f; sacc[ct][1]=0.f; sacc[ct][2]=0.f; sacc[ct][3]=0.f; }
        #pragma unroll
        for (int ct = 0; ct < 4; ++ct) {
            #pragma unroll
            for (int st = 0; st < 3; ++st) {
                bf16x8 kfrag = *(const bf16x8*)&Klds[(ct * 16 + lr) * 104 + st * 32 + lg * 8];
                sacc[ct] = __builtin_amdgcn_mfma_f32_16x16x32_bf16(qfrag[st], kfrag, sacc[ct], 0, 0, 0);
            }
        }

        float rs[4];
        #pragma unroll
        for (int j = 0; j < 4; ++j) {
            float mx = fmaxf(fmaxf(sacc[0][j], sacc[1][j]), fmaxf(sacc[2][j], sacc[3][j]));
            mx = fmaxf(mx, __shfl_xor(mx, 1));
            mx = fmaxf(mx, __shfl_xor(mx, 2));
            mx = fmaxf(mx, __shfl_xor(mx, 4));
            mx = fmaxf(mx, __shfl_xor(mx, 8));
            float nm = fmaxf(m_r[j], mx);
            rs[j] = __builtin_amdgcn_exp2f(m_r[j] - nm);
            m_r[j] = nm;
        }
        __hip_bfloat16* myP = Plds + wave * 16 * 72;
        #pragma unroll
        for (int j = 0; j < 4; ++j) {
            float p0 = __builtin_amdgcn_exp2f(sacc[0][j] - m_r[j]);
            float p1 = __builtin_amdgcn_exp2f(sacc[1][j] - m_r[j]);
            float p2 = __builtin_amdgcn_exp2f(sacc[2][j] - m_r[j]);
            float p3 = __builtin_amdgcn_exp2f(sacc[3][j] - m_r[j]);
            const int r = lg * 4 + j;
            myP[r * 72 +  0 + lr] = __float2bfloat16(p0);
            myP[r * 72 + 16 + lr] = __float2bfloat16(p1);
            myP[r * 72 + 32 + lr] = __float2bfloat16(p2);
            myP[r * 72 + 48 + lr] = __float2bfloat16(p3);
            float sum = p0 + p1 + p2 + p3;
            sum += __shfl_xor(sum, 1);
            sum += __shfl_xor(sum, 2);
            sum += __shfl_xor(sum, 4);
            sum += __shfl_xor(sum, 8);
            l_r[j] = l_r[j] * rs[j] + sum;
            oacc[0][j] *= rs[j]; oacc[1][j] *= rs[j];
            oacc[2][j] *= rs[j]; oacc[3][j] *= rs[j];
        }

        #pragma unroll
        for (int kk = 0; kk < 2; ++kk) {
            bf16x8 pfrag = *(const bf16x8*)&myP[lr * 72 + kk * 32 + lg * 8];
            #pragma unroll
            for (int ct = 0; ct < 4; ++ct) {
                bf16x8 vfrag = *(const bf16x8*)&Vlds[(ct * 16 + lr) * 72 + kk * 32 + lg * 8];
                oacc[ct] = __builtin_amdgcn_mfma_f32_16x16x32_bf16(pfrag, vfrag, oacc[ct], 0, 0, 0);
            }
        }
        __syncthreads();
    }

    #pragma unroll
    for (int j = 0; j < 4; ++j) {
        const float invl = 1.0f / l_r[j];
        const int q = qtile * 64 + wave * 16 + lg * 4 + j;
        float* op = out + ((long)b * SEQ + q) * 1024 + h * 64;
        op[ 0 + lr] = oacc[0][j] * invl;
        op[16 + lr] = oacc[1][j] * invl;
        op[32 + lr] = oacc[2][j] * invl;
        op[48 + lr] = oacc[3][j] * invl;
    }
}

extern "C" void kernel_launch(void* const* d_in, const int* in_sizes, int n_in,
                              void* d_out, int out_size, void* d_ws, size_t ws_size,
                              hipStream_t stream) {
    const float* qf    = (const float*)d_in[0];
    const float* kf    = (const float*)d_in[1];
    const float* qc    = (const float*)d_in[2];
    const float* kc    = (const float*)d_in[3];
    const float* vv    = (const float*)d_in[4];
    const float* alpha = (const float*)d_in[5];
    float* out = (float*)d_out;

    const int B = 2;
    if (ws_size >= KP_BYTES + VT_BYTES) {
        char* kp = (char*)d_ws;
        char* vt = (char*)d_ws + KP_BYTES;
        pack_kv<<<2 * B * NHEADS * NT, 256, 0, stream>>>(kf, kc, vv, kp, vt);
        stfa_v8<<<B * NHEADS * (SEQ / QBLK), 128, 0, stream>>>(qf, qc, alpha, kp, vt, out);
    } else {
        stfa_v1<<<B * NHEADS * (SEQ / 64), 256, 0, stream>>>(qf, kf, qc, kc, vv, alpha, out);
    }
}

// Round 10
// 67.030 us; speedup vs baseline: 1.3037x; 1.3037x over previous
//
#include <hip/hip_runtime.h>
#include <hip/hip_bf16.h>

typedef __bf16 bf16_t;
typedef bf16_t bf16x8 __attribute__((ext_vector_type(8)));
typedef float f32x4 __attribute__((ext_vector_type(4)));
typedef float f32x16 __attribute__((ext_vector_type(16)));

#define NHEADS 16
#define DFEAT 64
#define DCOORD 8
#define SEQ 2048
#define KVBLK 64
#define NT (SEQ / KVBLK)
#define QBLK 128                       // 4 waves = (qpair 0/1) x (s-half 0/1); 64 q per wave
#define KCOLS 80                       // K' cols: 64 feat + 8 coord + 8 zero
#define KROWB (KCOLS * 2)              // 160 B row stride
#define KTILEB (KVBLK * KROWB)         // 10240 B per K tile
#define VSTRB 80                       // V^T half-tile row stride (bytes): 32 s + 8 pad
#define VHALFB (DFEAT * VSTRB)         // 5120 B per s-half
#define VTILEB (2 * VHALFB)            // 10240 B per V tile

#define KP_BYTES ((size_t)32 * NT * KTILEB)   // 10,485,760
#define VT_BYTES ((size_t)32 * NT * VTILEB)   // 10,485,760

union Bf8 { bf16x8 v; __hip_bfloat16 e[8]; };
union U4  { unsigned u[4]; bf16x8 v; };

static __device__ inline unsigned pack2(float a, float b) {
    union { __hip_bfloat16 h[2]; unsigned u; } x;
    x.h[0] = __float2bfloat16(a); x.h[1] = __float2bfloat16(b);
    return x.u;
}

// ---------------------------------------------------------------------------
// Merged pre-pass: blocks [0,1024) pack K' tiles, [1024,2048) pack V^T tiles.
// K' tile [64][80] bf16, row bytes 160:
//   feat  region [0,128):  byte = row*160 + ((cc*32 | half*16) ^ ((row&7)<<4))
//   coord region [128,160): byte = row*160 + 128 + ((half*16) ^ ((row&1)<<4))
//   (write and read apply the SAME per-row key -> consistent, rule 21)
// V^T tile [sh][64 d][40] bf16 (stride 80 B), s-columns sigma-permuted
//   (bit2<->bit3 swap within the 32-s half; lane-local P packing, r5-verified).
//   Stride 80: d*80 mod 128 walks all 8 bank slots -> clean 4-way on reads.
// ---------------------------------------------------------------------------
__global__ __launch_bounds__(256)
void pack_kv(const float* __restrict__ kf, const float* __restrict__ kc,
             const float* __restrict__ v,
             char* __restrict__ kp, char* __restrict__ vt)
{
    __shared__ __align__(16) char tile[KTILEB];   // 10240 B
    const int bid = blockIdx.x;
    const int tid = threadIdx.x;

    if (bid < 1024) {
        // ---------------- K' pack ----------------
        const int blk = bid;               // [bh][t]
        const int t  = blk & (NT - 1);
        const int bh = blk >> 5;
        const int b = bh >> 4, h = bh & 15;
        #pragma unroll
        for (int it = 0; it < 2; ++it) {
            const int c = tid + it * 256;      // 320 chunk-pairs (row, cc)
            if (c < 320) {
                const int row = c / 5, cc = c - row * 5;
                const int s = t * KVBLK + row;
                float vv[16];
                if (cc < 4) {
                    const float* p = kf + ((long)b * SEQ + s) * (NHEADS * DFEAT) + h * DFEAT + cc * 16;
                    #pragma unroll
                    for (int i = 0; i < 4; ++i) {
                        float4 f = ((const float4*)p)[i];
                        vv[4*i+0]=f.x; vv[4*i+1]=f.y; vv[4*i+2]=f.z; vv[4*i+3]=f.w;
                    }
                } else {
                    const float* p = kc + ((long)b * SEQ + s) * (NHEADS * DCOORD) + h * DCOORD;
                    float4 f0 = ((const float4*)p)[0];
                    float4 f1 = ((const float4*)p)[1];
                    vv[0]=f0.x; vv[1]=f0.y; vv[2]=f0.z; vv[3]=f0.w;
                    vv[4]=f1.x; vv[5]=f1.y; vv[6]=f1.z; vv[7]=f1.w;
                    #pragma unroll
                    for (int i = 8; i < 16; ++i) vv[i] = 0.f;
                }
                Bf8 w0, w1;
                #pragma unroll
                for (int i = 0; i < 8; ++i) {
                    w0.e[i] = __float2bfloat16(vv[i]);
                    w1.e[i] = __float2bfloat16(vv[i + 8]);
                }
                if (cc < 4) {
                    const int key = (row & 7) << 4;
                    const int base = cc * 32;
                    *(bf16x8*)&tile[row * KROWB + ((base)      ^ key)] = w0.v;
                    *(bf16x8*)&tile[row * KROWB + ((base + 16) ^ key)] = w1.v;
                } else {
                    const int key = (row & 1) << 4;
                    *(bf16x8*)&tile[row * KROWB + 128 + ((0)  ^ key)] = w0.v;
                    *(bf16x8*)&tile[row * KROWB + 128 + ((16) ^ key)] = w1.v;
                }
            }
        }
        __syncthreads();
        const bf16x8* ti = (const bf16x8*)tile;
        bf16x8* o = (bf16x8*)(kp + (long)blk * KTILEB);
        #pragma unroll
        for (int j = 0; j < 3; ++j) {
            const int i = tid + 256 * j;
            if (i < 640) o[i] = ti[i];
        }
    } else {
        // ---------------- V^T pack ----------------
        const int blk = bid - 1024;        // [bh][t]
        const int t  = blk & (NT - 1);
        const int bh = blk >> 5;
        const int b = bh >> 4, h = bh & 15;
        const int s = tid >> 2, c = tid & 3;
        const int sh = s >> 5, sl = s & 31;
        const int slot = (sl & ~12) | ((sl & 4) << 1) | ((sl & 8) >> 1);  // swap bits 2,3
        const float* src = v + ((long)b * SEQ + t * KVBLK + s) * (NHEADS * DFEAT) + h * DFEAT;
        __hip_bfloat16* vtile = (__hip_bfloat16*)tile;
        #pragma unroll
        for (int c4 = 0; c4 < 4; ++c4) {
            float4 f = ((const float4*)src)[c4 * 4 + c];
            float vals[4] = {f.x, f.y, f.z, f.w};
            #pragma unroll
            for (int ii = 0; ii < 4; ++ii) {
                const int dd = c4 * 16 + c * 4 + ii;
                const int byte = sh * VHALFB + dd * VSTRB + slot * 2;
                vtile[byte >> 1] = __float2bfloat16(vals[ii]);
            }
        }
        __syncthreads();
        const bf16x8* ti = (const bf16x8*)tile;
        bf16x8* o = (bf16x8*)(vt + (long)blk * (long)VTILEB);
        #pragma unroll
        for (int j = 0; j < 3; ++j) {
            const int i = tid + 256 * j;
            if (i < 640) o[i] = ti[i];
        }
    }
}

// ---------------------------------------------------------------------------
// Main kernel v9b: s-split x q-reuse. 4 waves = (qpair) x (s-half); each wave
// computes 64 q (2 register q-sets) over its 32-s half of every KV tile.
// Each K/V LDS fragment read once feeds two MFMAs. 2048 waves total
// (2/SIMD, v5 TLP) with half of v5's LDS read traffic. Fixed-reference
// softmax; s-half (O,l) partials combined once at kernel end via LDS.
// (v9 compile fix: no LDS pointer arrays — compute buffer addresses inline.)
// ---------------------------------------------------------------------------
__global__ __launch_bounds__(256, 2)
void stfa_v9(const float* __restrict__ qf, const float* __restrict__ qc,
             const float* __restrict__ alpha,
             const char* __restrict__ kp, const char* __restrict__ vt,
             float* __restrict__ out)
{
    __shared__ __align__(16) char SMEM[2 * KTILEB + 2 * VTILEB];   // 40960 B

    const int tid  = threadIdx.x;
    const int wave = tid >> 6;
    const int lane = tid & 63;
    const int lq   = lane & 31;   // q column within a q-set
    const int hi   = lane >> 5;   // half-wave: k-slot select
    const int qp   = wave >> 1;   // q-pair (which 64 of the 128 q)
    const int sh   = wave & 1;    // s-half of each KV tile

    const int dd    = blockIdx.x;     // [qtile(4b)][bh(5b)]: same-bh -> same XCD
    const int bh    = dd & 31;
    const int qtile = dd >> 5;        // 0..15
    const int b = bh >> 4, h = bh & 15;

    const float a_h      = alpha[h];
    const float LOG2E    = 1.4426950408889634f;
    const float qf_scale = 0.125f * LOG2E;
    const float qc_scale = a_h * 0.35355339059327373f * LOG2E;

    const char* kp_bh = kp + (long)bh * NT * KTILEB;
    const char* vt_bh = vt + (long)bh * NT * VTILEB;

    auto stage = [&](int bb, int t) {
        const char* kg = kp_bh + (long)t * KTILEB;
        const char* vg = vt_bh + (long)t * VTILEB;
        char* kl = SMEM + bb * KTILEB;
        char* vl = SMEM + 2 * KTILEB + bb * VTILEB;
        #pragma unroll
        for (int j = 0; j < 3; ++j) {            // 10 x 1KB K chunks
            const int i = wave + 4 * j;
            if (i < 10)
                __builtin_amdgcn_global_load_lds(
                    (const __attribute__((address_space(1))) void*)(kg + i * 1024 + lane * 16),
                    (__attribute__((address_space(3))) void*)(kl + i * 1024), 16, 0, 0);
        }
        #pragma unroll
        for (int j = 0; j < 3; ++j) {            // 10 x 1KB V chunks
            const int i = wave + 4 * j;
            if (i < 10)
                __builtin_amdgcn_global_load_lds(
                    (const __attribute__((address_space(1))) void*)(vg + i * 1024 + lane * 16),
                    (__attribute__((address_space(3))) void*)(vl + i * 1024), 16, 0, 0);
        }
    };

    stage(0, 0);

    // ---- Q' fragments for both q-sets (A: qp*64+lq, B: +32) ----
    const int qrowA = qtile * QBLK + qp * 64 + lq;
    const int qrowB = qrowA + 32;

    bf16x8 qfragA[5], qfragB[5];
    #pragma unroll
    for (int set = 0; set < 2; ++set) {
        const int qrow = set ? qrowB : qrowA;
        const float* qfp = qf + ((long)b * SEQ + qrow) * (NHEADS * DFEAT) + h * DFEAT;
        const float* qcp = qc + ((long)b * SEQ + qrow) * (NHEADS * DCOORD) + h * DCOORD;
        #pragma unroll
        for (int ks = 0; ks < 4; ++ks) {
            const float* p = qfp + ks * 16 + hi * 8;
            float4 f0 = *(const float4*)p;
            float4 f1 = *(const float4*)(p + 4);
            Bf8 q;
            q.e[0] = __float2bfloat16(f0.x * qf_scale); q.e[1] = __float2bfloat16(f0.y * qf_scale);
            q.e[2] = __float2bfloat16(f0.z * qf_scale); q.e[3] = __float2bfloat16(f0.w * qf_scale);
            q.e[4] = __float2bfloat16(f1.x * qf_scale); q.e[5] = __float2bfloat16(f1.y * qf_scale);
            q.e[6] = __float2bfloat16(f1.z * qf_scale); q.e[7] = __float2bfloat16(f1.w * qf_scale);
            if (set) qfragB[ks] = q.v; else qfragA[ks] = q.v;
        }
        Bf8 q;
        #pragma unroll
        for (int i = 0; i < 8; ++i) q.e[i] = __float2bfloat16(0.0f);
        if (hi == 0) {   // k = 64..71 = coord; k = 72..79 stays zero
            float4 c0 = *(const float4*)qcp;
            float4 c1 = *(const float4*)(qcp + 4);
            q.e[0] = __float2bfloat16(c0.x * qc_scale); q.e[1] = __float2bfloat16(c0.y * qc_scale);
            q.e[2] = __float2bfloat16(c0.z * qc_scale); q.e[3] = __float2bfloat16(c0.w * qc_scale);
            q.e[4] = __float2bfloat16(c1.x * qc_scale); q.e[5] = __float2bfloat16(c1.y * qc_scale);
            q.e[6] = __float2bfloat16(c1.z * qc_scale); q.e[7] = __float2bfloat16(c1.w * qc_scale);
        }
        if (set) qfragB[4] = q.v; else qfragA[4] = q.v;
    }

    f32x16 oaccA[2], oaccB[2];
    #pragma unroll
    for (int dt = 0; dt < 2; ++dt)
        #pragma unroll
        for (int r = 0; r < 16; ++r) { oaccA[dt][r] = 0.f; oaccB[dt][r] = 0.f; }
    float lA = 0.f, lB = 0.f;

    __syncthreads();   // tile 0 resident

    for (int t = 0; t < NT; ++t) {
        const int bb = t & 1;
        if (t + 1 < NT) stage(bb ^ 1, t + 1);

        const char* kl = SMEM + bb * KTILEB;
        const char* vl = SMEM + 2 * KTILEB + bb * VTILEB;

        // ---- QK'^T: wave's s-half, 5 k-steps; each kfrag feeds both q-sets ----
        f32x16 saccA, saccB;
        #pragma unroll
        for (int r = 0; r < 16; ++r) { saccA[r] = 0.f; saccB[r] = 0.f; }
        const int krow = sh * 32 + lq;
        __builtin_amdgcn_s_setprio(1);
        #pragma unroll
        for (int ks = 0; ks < 5; ++ks) {
            int off;
            if (ks < 4) off = (ks * 32 + hi * 16) ^ ((lq & 7) << 4);
            else        off = 128 + ((hi * 16) ^ ((lq & 1) << 4));
            bf16x8 kfrag = *(const bf16x8*)&kl[krow * KROWB + off];
            saccA = __builtin_amdgcn_mfma_f32_32x32x16_bf16(kfrag, qfragA[ks], saccA, 0, 0, 0);
            saccB = __builtin_amdgcn_mfma_f32_32x32x16_bf16(kfrag, qfragB[ks], saccB, 0, 0, 0);
        }
        __builtin_amdgcn_s_setprio(0);

        // ---- P = exp2(S); lane-local pack (sigma baked into V halves) ----
        bf16x8 pfragA[2], pfragB[2];
        {
            float p[16];
            #pragma unroll
            for (int r = 0; r < 16; ++r) p[r] = __builtin_amdgcn_exp2f(saccA[r]);
            U4 fa, fb;
            #pragma unroll
            for (int i = 0; i < 4; ++i) {
                fa.u[i] = pack2(p[2 * i],     p[2 * i + 1]);
                fb.u[i] = pack2(p[2 * i + 8], p[2 * i + 9]);
            }
            pfragA[0] = fa.v; pfragA[1] = fb.v;
            float s8[8];
            #pragma unroll
            for (int r = 0; r < 8; ++r) s8[r] = p[r] + p[r + 8];
            float s4[4];
            #pragma unroll
            for (int r = 0; r < 4; ++r) s4[r] = s8[r] + s8[r + 4];
            lA += (s4[0] + s4[1]) + (s4[2] + s4[3]);
        }
        {
            float p[16];
            #pragma unroll
            for (int r = 0; r < 16; ++r) p[r] = __builtin_amdgcn_exp2f(saccB[r]);
            U4 fa, fb;
            #pragma unroll
            for (int i = 0; i < 4; ++i) {
                fa.u[i] = pack2(p[2 * i],     p[2 * i + 1]);
                fb.u[i] = pack2(p[2 * i + 8], p[2 * i + 9]);
            }
            pfragB[0] = fa.v; pfragB[1] = fb.v;
            float s8[8];
            #pragma unroll
            for (int r = 0; r < 8; ++r) s8[r] = p[r] + p[r + 8];
            float s4[4];
            #pragma unroll
            for (int r = 0; r < 4; ++r) s4[r] = s8[r] + s8[r + 4];
            lB += (s4[0] + s4[1]) + (s4[2] + s4[3]);
        }

        // ---- PV: 2 d-tiles x 2 k-steps on wave's V half; vfrag feeds both sets ----
        __builtin_amdgcn_s_setprio(1);
        #pragma unroll
        for (int dt = 0; dt < 2; ++dt) {
            const int row = dt * 32 + lq;
            #pragma unroll
            for (int ks = 0; ks < 2; ++ks) {
                bf16x8 vfrag = *(const bf16x8*)&vl[sh * VHALFB + row * VSTRB + ks * 32 + hi * 16];
                oaccA[dt] = __builtin_amdgcn_mfma_f32_32x32x16_bf16(vfrag, pfragA[ks], oaccA[dt], 0, 0, 0);
                oaccB[dt] = __builtin_amdgcn_mfma_f32_32x32x16_bf16(vfrag, pfragB[ks], oaccB[dt], 0, 0, 0);
            }
        }
        __builtin_amdgcn_s_setprio(0);

        __syncthreads();   // drains staged loads; frees buf bb
    }

    // ---- combine s-half partials (intra-wave hi halves first) ----
    float lA2 = lA + __shfl_xor(lA, 32);
    float lB2 = lB + __shfl_xor(lB, 32);

    float* sO = (float*)SMEM;                 // 2 qp x 2 set x 64 lanes x 32 f32 = 32 KB
    float* sL = (float*)(SMEM + 32768);       // 2 qp x 2 set x 64 f32 = 1 KB
    if (sh == 1) {
        float* dst = sO + ((qp * 2 + 0) * 64 + lane) * 32;
        #pragma unroll
        for (int dt = 0; dt < 2; ++dt)
            #pragma unroll
            for (int r = 0; r < 16; ++r) dst[dt * 16 + r] = oaccA[dt][r];
        dst = sO + ((qp * 2 + 1) * 64 + lane) * 32;
        #pragma unroll
        for (int dt = 0; dt < 2; ++dt)
            #pragma unroll
            for (int r = 0; r < 16; ++r) dst[dt * 16 + r] = oaccB[dt][r];
        sL[(qp * 2 + 0) * 64 + lane] = lA2;
        sL[(qp * 2 + 1) * 64 + lane] = lB2;
    }
    __syncthreads();
    if (sh == 0) {
        // ---- q-set A ----
        {
            const float* src = sO + ((qp * 2 + 0) * 64 + lane) * 32;
            #pragma unroll
            for (int dt = 0; dt < 2; ++dt)
                #pragma unroll
                for (int r = 0; r < 16; ++r) oaccA[dt][r] += src[dt * 16 + r];
            const float lT = lA2 + sL[(qp * 2 + 0) * 64 + lane];
            const float invl = 1.0f / lT;
            float* ob = out + ((long)b * SEQ + qrowA) * (NHEADS * DFEAT) + h * DFEAT;
            #pragma unroll
            for (int dt = 0; dt < 2; ++dt) {
                #pragma unroll
                for (int g = 0; g < 4; ++g) {
                    const int d0 = dt * 32 + g * 8 + hi * 4;
                    float4 o;
                    o.x = oaccA[dt][4 * g + 0] * invl;
                    o.y = oaccA[dt][4 * g + 1] * invl;
                    o.z = oaccA[dt][4 * g + 2] * invl;
                    o.w = oaccA[dt][4 * g + 3] * invl;
                    *(float4*)(ob + d0) = o;
                }
            }
        }
        // ---- q-set B ----
        {
            const float* src = sO + ((qp * 2 + 1) * 64 + lane) * 32;
            #pragma unroll
            for (int dt = 0; dt < 2; ++dt)
                #pragma unroll
                for (int r = 0; r < 16; ++r) oaccB[dt][r] += src[dt * 16 + r];
            const float lT = lB2 + sL[(qp * 2 + 1) * 64 + lane];
            const float invl = 1.0f / lT;
            float* ob = out + ((long)b * SEQ + qrowB) * (NHEADS * DFEAT) + h * DFEAT;
            #pragma unroll
            for (int dt = 0; dt < 2; ++dt) {
                #pragma unroll
                for (int g = 0; g < 4; ++g) {
                    const int d0 = dt * 32 + g * 8 + hi * 4;
                    float4 o;
                    o.x = oaccB[dt][4 * g + 0] * invl;
                    o.y = oaccB[dt][4 * g + 1] * invl;
                    o.z = oaccB[dt][4 * g + 2] * invl;
                    o.w = oaccB[dt][4 * g + 3] * invl;
                    *(float4*)(ob + d0) = o;
                }
            }
        }
    }
}

// ---------------------------------------------------------------------------
// v1 fallback (round-1 kernel, proven) if ws is too small for pack buffers.
// ---------------------------------------------------------------------------
__global__ __launch_bounds__(256)
void stfa_v1(const float* __restrict__ qf, const float* __restrict__ kf,
             const float* __restrict__ qc, const float* __restrict__ kc,
             const float* __restrict__ vv, const float* __restrict__ alpha,
             float* __restrict__ out)
{
    __shared__ __align__(16) __hip_bfloat16 Klds[64 * 104];
    __shared__ __align__(16) __hip_bfloat16 Vlds[64 * 72];
    __shared__ __align__(16) __hip_bfloat16 Plds[4 * 16 * 72];

    const int tid  = threadIdx.x;
    const int wave = tid >> 6;
    const int lane = tid & 63;
    const int lr   = lane & 15;
    const int lg   = lane >> 4;

    const int blk   = blockIdx.x;
    const int qtile = blk & 31;
    const int h     = (blk >> 5) & 15;
    const int b     = blk >> 9;

    for (int i = tid; i < 64 * 104; i += 256) Klds[i] = __float2bfloat16(0.0f);

    const float a_h      = alpha[h];
    const float LOG2E    = 1.4426950408889634f;
    const float qf_scale = 0.125f * LOG2E;
    const float qc_scale = a_h * 0.35355339059327373f * LOG2E;

    const int qrow = qtile * 64 + wave * 16 + lr;
    const float* qf_p = qf + ((long)b * SEQ + qrow) * 1024 + h * 64;
    const float* qc_p = qc + ((long)b * SEQ + qrow) * 128 + h * 8;

    bf16x8 qfrag[3];
    #pragma unroll
    for (int st = 0; st < 2; ++st) {
        const float* p = qf_p + st * 32 + lg * 8;
        float4 f0 = *(const float4*)p;
        float4 f1 = *(const float4*)(p + 4);
        Bf8 q;
        q.e[0] = __float2bfloat16(f0.x * qf_scale); q.e[1] = __float2bfloat16(f0.y * qf_scale);
        q.e[2] = __float2bfloat16(f0.z * qf_scale); q.e[3] = __float2bfloat16(f0.w * qf_scale);
        q.e[4] = __float2bfloat16(f1.x * qf_scale); q.e[5] = __float2bfloat16(f1.y * qf_scale);
        q.e[6] = __float2bfloat16(f1.z * qf_scale); q.e[7] = __float2bfloat16(f1.w * qf_scale);
        qfrag[st] = q.v;
    }
    {
        Bf8 q;
        #pragma unroll
        for (int i = 0; i < 8; ++i) q.e[i] = __float2bfloat16(0.0f);
        if (lg == 0) {
            float4 c0 = *(const float4*)qc_p;
            float4 c1 = *(const float4*)(qc_p + 4);
            q.e[0] = __float2bfloat16(c0.x * qc_scale); q.e[1] = __float2bfloat16(c0.y * qc_scale);
            q.e[2] = __float2bfloat16(c0.z * qc_scale); q.e[3] = __float2bfloat16(c0.w * qc_scale);
            q.e[4] = __float2bfloat16(c1.x * qc_scale); q.e[5] = __float2bfloat16(c1.y * qc_scale);
            q.e[6] = __float2bfloat16(c1.z * qc_scale); q.e[7] = __float2bfloat16(c1.w * qc_scale);
        }
        qfrag[2] = q.v;
    }

    const float* kf_b = kf + (long)b * SEQ * 1024 + h * 64;
    const float* kc_b = kc + (long)b * SEQ * 128 + h * 8;
    const float* v_b  = vv + (long)b * SEQ * 1024 + h * 64;

    f32x4 oacc[4];
    #pragma unroll
    for (int ct = 0; ct < 4; ++ct) { oacc[ct][0]=0.f; oacc[ct][1]=0.f; oacc[ct][2]=0.f; oacc[ct][3]=0.f; }
    float m_r[4], l_r[4];
    #pragma unroll
    for (int j = 0; j < 4; ++j) { m_r[j] = -3.0e38f; l_r[j] = 0.f; }

    __syncthreads();

    for (int s0 = 0; s0 < SEQ; s0 += 64) {
        {
            const int srow = tid >> 2, ch = tid & 3;
            const float* p = kf_b + (long)(s0 + srow) * 1024 + ch * 16;
            float4 f0 = ((const float4*)p)[0];
            float4 f1 = ((const float4*)p)[1];
            float4 f2 = ((const float4*)p)[2];
            float4 f3 = ((const float4*)p)[3];
            Bf8 w0, w1;
            w0.e[0]=__float2bfloat16(f0.x); w0.e[1]=__float2bfloat16(f0.y);
            w0.e[2]=__float2bfloat16(f0.z); w0.e[3]=__float2bfloat16(f0.w);
            w0.e[4]=__float2bfloat16(f1.x); w0.e[5]=__float2bfloat16(f1.y);
            w0.e[6]=__float2bfloat16(f1.z); w0.e[7]=__float2bfloat16(f1.w);
            w1.e[0]=__float2bfloat16(f2.x); w1.e[1]=__float2bfloat16(f2.y);
            w1.e[2]=__float2bfloat16(f2.z); w1.e[3]=__float2bfloat16(f2.w);
            w1.e[4]=__float2bfloat16(f3.x); w1.e[5]=__float2bfloat16(f3.y);
            w1.e[6]=__float2bfloat16(f3.z); w1.e[7]=__float2bfloat16(f3.w);
            *(bf16x8*)&Klds[srow * 104 + ch * 16]     = w0.v;
            *(bf16x8*)&Klds[srow * 104 + ch * 16 + 8] = w1.v;
        }
        {
            const int srow = tid >> 2, cp = (tid & 3) * 2;
            const float* p = kc_b + (long)(s0 + srow) * 128 + cp;
            float2 c = *(const float2*)p;
            Klds[srow * 104 + 64 + cp]     = __float2bfloat16(c.x);
            Klds[srow * 104 + 64 + cp + 1] = __float2bfloat16(c.y);
        }
        {
            const int srow = tid & 63, d0 = (tid >> 6) * 16;
            const float* p = v_b + (long)(s0 + srow) * 1024 + d0;
            #pragma unroll
            for (int c4 = 0; c4 < 4; ++c4) {
                float4 f = ((const float4*)p)[c4];
                Vlds[(d0 + c4 * 4 + 0) * 72 + srow] = __float2bfloat16(f.x);
                Vlds[(d0 + c4 * 4 + 1) * 72 + srow] = __float2bfloat16(f.y);
                Vlds[(d0 + c4 * 4 + 2) * 72 + srow] = __float2bfloat16(f.z);
                Vlds[(d0 + c4 * 4 + 3) * 72 + srow] = __float2bfloat16(f.w);
            }
        }
        __syncthreads();

        f32x4 sacc[4];
        #pragma unroll
        for (int ct = 0; ct < 4; ++ct) { sacc[ct][0]=0.f; sacc[ct][1]=0.f; sacc[ct][2]=0.f; sacc[ct][3]=0.f; }
        #pragma unroll
        for (int ct = 0; ct < 4; ++ct) {
            #pragma unroll
            for (int st = 0; st < 3; ++st) {
                bf16x8 kfrag = *(const bf16x8*)&Klds[(ct * 16 + lr) * 104 + st * 32 + lg * 8];
                sacc[ct] = __builtin_amdgcn_mfma_f32_16x16x32_bf16(qfrag[st], kfrag, sacc[ct], 0, 0, 0);
            }
        }

        float rs[4];
        #pragma unroll
        for (int j = 0; j < 4; ++j) {
            float mx = fmaxf(fmaxf(sacc[0][j], sacc[1][j]), fmaxf(sacc[2][j], sacc[3][j]));
            mx = fmaxf(mx, __shfl_xor(mx, 1));
            mx = fmaxf(mx, __shfl_xor(mx, 2));
            mx = fmaxf(mx, __shfl_xor(mx, 4));
            mx = fmaxf(mx, __shfl_xor(mx, 8));
            float nm = fmaxf(m_r[j], mx);
            rs[j] = __builtin_amdgcn_exp2f(m_r[j] - nm);
            m_r[j] = nm;
        }
        __hip_bfloat16* myP = Plds + wave * 16 * 72;
        #pragma unroll
        for (int j = 0; j < 4; ++j) {
            float p0 = __builtin_amdgcn_exp2f(sacc[0][j] - m_r[j]);
            float p1 = __builtin_amdgcn_exp2f(sacc[1][j] - m_r[j]);
            float p2 = __builtin_amdgcn_exp2f(sacc[2][j] - m_r[j]);
            float p3 = __builtin_amdgcn_exp2f(sacc[3][j] - m_r[j]);
            const int r = lg * 4 + j;
            myP[r * 72 +  0 + lr] = __float2bfloat16(p0);
            myP[r * 72 + 16 + lr] = __float2bfloat16(p1);
            myP[r * 72 + 32 + lr] = __float2bfloat16(p2);
            myP[r * 72 + 48 + lr] = __float2bfloat16(p3);
            float sum = p0 + p1 + p2 + p3;
            sum += __shfl_xor(sum, 1);
            sum += __shfl_xor(sum, 2);
            sum += __shfl_xor(sum, 4);
            sum += __shfl_xor(sum, 8);
            l_r[j] = l_r[j] * rs[j] + sum;
            oacc[0][j] *= rs[j]; oacc[1][j] *= rs[j];
            oacc[2][j] *= rs[j]; oacc[3][j] *= rs[j];
        }

        #pragma unroll
        for (int kk = 0; kk < 2; ++kk) {
            bf16x8 pfrag = *(const bf16x8*)&myP[lr * 72 + kk * 32 + lg * 8];
            #pragma unroll
            for (int ct = 0; ct < 4; ++ct) {
                bf16x8 vfrag = *(const bf16x8*)&Vlds[(ct * 16 + lr) * 72 + kk * 32 + lg * 8];
                oacc[ct] = __builtin_amdgcn_mfma_f32_16x16x32_bf16(pfrag, vfrag, oacc[ct], 0, 0, 0);
            }
        }
        __syncthreads();
    }

    #pragma unroll
    for (int j = 0; j < 4; ++j) {
        const float invl = 1.0f / l_r[j];
        const int q = qtile * 64 + wave * 16 + lg * 4 + j;
        float* op = out + ((long)b * SEQ + q) * 1024 + h * 64;
        op[ 0 + lr] = oacc[0][j] * invl;
        op[16 + lr] = oacc[1][j] * invl;
        op[32 + lr] = oacc[2][j] * invl;
        op[48 + lr] = oacc[3][j] * invl;
    }
}

extern "C" void kernel_launch(void* const* d_in, const int* in_sizes, int n_in,
                              void* d_out, int out_size, void* d_ws, size_t ws_size,
                              hipStream_t stream) {
    const float* qf    = (const float*)d_in[0];
    const float* kf    = (const float*)d_in[1];
    const float* qc    = (const float*)d_in[2];
    const float* kc    = (const float*)d_in[3];
    const float* vv    = (const float*)d_in[4];
    const float* alpha = (const float*)d_in[5];
    float* out = (float*)d_out;

    const int B = 2;
    if (ws_size >= KP_BYTES + VT_BYTES) {
        char* kp = (char*)d_ws;
        char* vt = (char*)d_ws + KP_BYTES;
        pack_kv<<<2 * B * NHEADS * NT, 256, 0, stream>>>(kf, kc, vv, kp, vt);
        stfa_v9<<<B * NHEADS * (SEQ / QBLK), 256, 0, stream>>>(qf, qc, alpha, kp, vt, out);
    } else {
        stfa_v1<<<B * NHEADS * (SEQ / 64), 256, 0, stream>>>(qf, kf, qc, kc, vv, alpha, out);
    }
}

// Round 11
// 66.731 us; speedup vs baseline: 1.3095x; 1.0045x over previous
//
#include <hip/hip_runtime.h>
#include <hip/hip_bf16.h>

typedef __bf16 bf16_t;
typedef bf16_t bf16x8 __attribute__((ext_vector_type(8)));
typedef float f32x4 __attribute__((ext_vector_type(4)));
typedef float f32x16 __attribute__((ext_vector_type(16)));

#define NHEADS 16
#define DFEAT 64
#define DCOORD 8
#define SEQ 2048
#define KVBLK 64
#define NT (SEQ / KVBLK)
#define QBLK 128                       // 4 waves = (qpair 0/1) x (s-half 0/1); 64 q per wave
#define KCOLS 80                       // K' cols: 64 feat + 8 coord + 8 zero
#define KROWB (KCOLS * 2)              // 160 B row stride
#define KTILEB (KVBLK * KROWB)         // 10240 B per K tile
#define VSTRB 80                       // V^T half-tile row stride (bytes): 32 s + 8 pad
#define VHALFB (DFEAT * VSTRB)         // 5120 B per s-half
#define VTILEB (2 * VHALFB)            // 10240 B per V tile

#define KP_BYTES ((size_t)32 * NT * KTILEB)   // 10,485,760
#define VT_BYTES ((size_t)32 * NT * VTILEB)   // 10,485,760

union Bf8 { bf16x8 v; __hip_bfloat16 e[8]; };
union U4  { unsigned u[4]; bf16x8 v; };

static __device__ inline unsigned pack2(float a, float b) {
    union { __hip_bfloat16 h[2]; unsigned u; } x;
    x.h[0] = __float2bfloat16(a); x.h[1] = __float2bfloat16(b);
    return x.u;
}

// ---------------------------------------------------------------------------
// Merged pre-pass (v9-verified, unchanged): blocks [0,1024) pack K' tiles,
// [1024,2048) pack V^T tiles.
// ---------------------------------------------------------------------------
__global__ __launch_bounds__(256)
void pack_kv(const float* __restrict__ kf, const float* __restrict__ kc,
             const float* __restrict__ v,
             char* __restrict__ kp, char* __restrict__ vt)
{
    __shared__ __align__(16) char tile[KTILEB];   // 10240 B
    const int bid = blockIdx.x;
    const int tid = threadIdx.x;

    if (bid < 1024) {
        // ---------------- K' pack ----------------
        const int blk = bid;               // [bh][t]
        const int t  = blk & (NT - 1);
        const int bh = blk >> 5;
        const int b = bh >> 4, h = bh & 15;
        #pragma unroll
        for (int it = 0; it < 2; ++it) {
            const int c = tid + it * 256;      // 320 chunk-pairs (row, cc)
            if (c < 320) {
                const int row = c / 5, cc = c - row * 5;
                const int s = t * KVBLK + row;
                float vv[16];
                if (cc < 4) {
                    const float* p = kf + ((long)b * SEQ + s) * (NHEADS * DFEAT) + h * DFEAT + cc * 16;
                    #pragma unroll
                    for (int i = 0; i < 4; ++i) {
                        float4 f = ((const float4*)p)[i];
                        vv[4*i+0]=f.x; vv[4*i+1]=f.y; vv[4*i+2]=f.z; vv[4*i+3]=f.w;
                    }
                } else {
                    const float* p = kc + ((long)b * SEQ + s) * (NHEADS * DCOORD) + h * DCOORD;
                    float4 f0 = ((const float4*)p)[0];
                    float4 f1 = ((const float4*)p)[1];
                    vv[0]=f0.x; vv[1]=f0.y; vv[2]=f0.z; vv[3]=f0.w;
                    vv[4]=f1.x; vv[5]=f1.y; vv[6]=f1.z; vv[7]=f1.w;
                    #pragma unroll
                    for (int i = 8; i < 16; ++i) vv[i] = 0.f;
                }
                Bf8 w0, w1;
                #pragma unroll
                for (int i = 0; i < 8; ++i) {
                    w0.e[i] = __float2bfloat16(vv[i]);
                    w1.e[i] = __float2bfloat16(vv[i + 8]);
                }
                if (cc < 4) {
                    const int key = (row & 7) << 4;
                    const int base = cc * 32;
                    *(bf16x8*)&tile[row * KROWB + ((base)      ^ key)] = w0.v;
                    *(bf16x8*)&tile[row * KROWB + ((base + 16) ^ key)] = w1.v;
                } else {
                    const int key = (row & 1) << 4;
                    *(bf16x8*)&tile[row * KROWB + 128 + ((0)  ^ key)] = w0.v;
                    *(bf16x8*)&tile[row * KROWB + 128 + ((16) ^ key)] = w1.v;
                }
            }
        }
        __syncthreads();
        const bf16x8* ti = (const bf16x8*)tile;
        bf16x8* o = (bf16x8*)(kp + (long)blk * KTILEB);
        #pragma unroll
        for (int j = 0; j < 3; ++j) {
            const int i = tid + 256 * j;
            if (i < 640) o[i] = ti[i];
        }
    } else {
        // ---------------- V^T pack ----------------
        const int blk = bid - 1024;        // [bh][t]
        const int t  = blk & (NT - 1);
        const int bh = blk >> 5;
        const int b = bh >> 4, h = bh & 15;
        const int s = tid >> 2, c = tid & 3;
        const int sh = s >> 5, sl = s & 31;
        const int slot = (sl & ~12) | ((sl & 4) << 1) | ((sl & 8) >> 1);  // swap bits 2,3
        const float* src = v + ((long)b * SEQ + t * KVBLK + s) * (NHEADS * DFEAT) + h * DFEAT;
        __hip_bfloat16* vtile = (__hip_bfloat16*)tile;
        #pragma unroll
        for (int c4 = 0; c4 < 4; ++c4) {
            float4 f = ((const float4*)src)[c4 * 4 + c];
            float vals[4] = {f.x, f.y, f.z, f.w};
            #pragma unroll
            for (int ii = 0; ii < 4; ++ii) {
                const int dd = c4 * 16 + c * 4 + ii;
                const int byte = sh * VHALFB + dd * VSTRB + slot * 2;
                vtile[byte >> 1] = __float2bfloat16(vals[ii]);
            }
        }
        __syncthreads();
        const bf16x8* ti = (const bf16x8*)tile;
        bf16x8* o = (bf16x8*)(vt + (long)blk * (long)VTILEB);
        #pragma unroll
        for (int j = 0; j < 3; ++j) {
            const int i = tid + 256 * j;
            if (i < 640) o[i] = ti[i];
        }
    }
}

// ---------------------------------------------------------------------------
// Main kernel v10: v9's s-split x q-reuse geometry + cross-tile pipelining.
// Per barrier region: QK(t+1) [MFMA, independent] || softmax(t) [VALU] ||
// PV(t) [MFMA]. Triple-buffered LDS (61,440 B; 2 blocks/CU) lets stage(t+2)
// issue right after the barrier with a full iteration to land -> ONE barrier
// per tile and vmcnt(0) that waits on nothing. 2x unrolled loop with
// role-swapped sacc registers (no cross-iteration copies).
// ---------------------------------------------------------------------------
__global__ __launch_bounds__(256, 2)
void stfa_v10(const float* __restrict__ qf, const float* __restrict__ qc,
              const float* __restrict__ alpha,
              const char* __restrict__ kp, const char* __restrict__ vt,
              float* __restrict__ out)
{
    __shared__ __align__(16) char SMEM[3 * KTILEB + 3 * VTILEB];   // 61440 B

    const int tid  = threadIdx.x;
    const int wave = tid >> 6;
    const int lane = tid & 63;
    const int lq   = lane & 31;   // q column within a q-set
    const int hi   = lane >> 5;   // half-wave: k-slot select
    const int qp   = wave >> 1;   // q-pair (which 64 of the 128 q)
    const int sh   = wave & 1;    // s-half of each KV tile

    const int dd    = blockIdx.x;     // [qtile(4b)][bh(5b)]: same-bh -> same XCD
    const int bh    = dd & 31;
    const int qtile = dd >> 5;        // 0..15
    const int b = bh >> 4, h = bh & 15;

    const float a_h      = alpha[h];
    const float LOG2E    = 1.4426950408889634f;
    const float qf_scale = 0.125f * LOG2E;
    const float qc_scale = a_h * 0.35355339059327373f * LOG2E;

    const char* kp_bh = kp + (long)bh * NT * KTILEB;
    const char* vt_bh = vt + (long)bh * NT * VTILEB;

    // 20 x 1KB chunks (10 K + 10 V), exactly 5 per wave.
    auto stage = [&](int tt) {
        const int m = tt % 3;
        const char* kg = kp_bh + (long)tt * KTILEB;
        const char* vg = vt_bh + (long)tt * VTILEB;
        char* kl = SMEM + m * KTILEB;
        char* vl = SMEM + 3 * KTILEB + m * VTILEB;
        #pragma unroll
        for (int j = 0; j < 5; ++j) {
            const int c = wave + 4 * j;
            if (c < 10) {
                __builtin_amdgcn_global_load_lds(
                    (const __attribute__((address_space(1))) void*)(kg + c * 1024 + lane * 16),
                    (__attribute__((address_space(3))) void*)(kl + c * 1024), 16, 0, 0);
            } else {
                const int i = c - 10;
                __builtin_amdgcn_global_load_lds(
                    (const __attribute__((address_space(1))) void*)(vg + i * 1024 + lane * 16),
                    (__attribute__((address_space(3))) void*)(vl + i * 1024), 16, 0, 0);
            }
        }
    };

    stage(0);
    stage(1);

    // ---- Q' fragments for both q-sets (A: qp*64+lq, B: +32) ----
    const int qrowA = qtile * QBLK + qp * 64 + lq;
    const int qrowB = qrowA + 32;

    bf16x8 qfragA[5], qfragB[5];
    #pragma unroll
    for (int set = 0; set < 2; ++set) {
        const int qrow = set ? qrowB : qrowA;
        const float* qfp = qf + ((long)b * SEQ + qrow) * (NHEADS * DFEAT) + h * DFEAT;
        const float* qcp = qc + ((long)b * SEQ + qrow) * (NHEADS * DCOORD) + h * DCOORD;
        #pragma unroll
        for (int ks = 0; ks < 4; ++ks) {
            const float* p = qfp + ks * 16 + hi * 8;
            float4 f0 = *(const float4*)p;
            float4 f1 = *(const float4*)(p + 4);
            Bf8 q;
            q.e[0] = __float2bfloat16(f0.x * qf_scale); q.e[1] = __float2bfloat16(f0.y * qf_scale);
            q.e[2] = __float2bfloat16(f0.z * qf_scale); q.e[3] = __float2bfloat16(f0.w * qf_scale);
            q.e[4] = __float2bfloat16(f1.x * qf_scale); q.e[5] = __float2bfloat16(f1.y * qf_scale);
            q.e[6] = __float2bfloat16(f1.z * qf_scale); q.e[7] = __float2bfloat16(f1.w * qf_scale);
            if (set) qfragB[ks] = q.v; else qfragA[ks] = q.v;
        }
        Bf8 q;
        #pragma unroll
        for (int i = 0; i < 8; ++i) q.e[i] = __float2bfloat16(0.0f);
        if (hi == 0) {   // k = 64..71 = coord; k = 72..79 stays zero
            float4 c0 = *(const float4*)qcp;
            float4 c1 = *(const float4*)(qcp + 4);
            q.e[0] = __float2bfloat16(c0.x * qc_scale); q.e[1] = __float2bfloat16(c0.y * qc_scale);
            q.e[2] = __float2bfloat16(c0.z * qc_scale); q.e[3] = __float2bfloat16(c0.w * qc_scale);
            q.e[4] = __float2bfloat16(c1.x * qc_scale); q.e[5] = __float2bfloat16(c1.y * qc_scale);
            q.e[6] = __float2bfloat16(c1.z * qc_scale); q.e[7] = __float2bfloat16(c1.w * qc_scale);
        }
        if (set) qfragB[4] = q.v; else qfragA[4] = q.v;
    }

    f32x16 oaccA[2], oaccB[2];
    #pragma unroll
    for (int dt = 0; dt < 2; ++dt)
        #pragma unroll
        for (int r = 0; r < 16; ++r) { oaccA[dt][r] = 0.f; oaccB[dt][r] = 0.f; }
    float lA = 0.f, lB = 0.f;

    auto qk = [&](int tt, f32x16& A, f32x16& B) {
        const char* kl = SMEM + (tt % 3) * KTILEB;
        #pragma unroll
        for (int r = 0; r < 16; ++r) { A[r] = 0.f; B[r] = 0.f; }
        const int krow = sh * 32 + lq;
        #pragma unroll
        for (int ks = 0; ks < 5; ++ks) {
            int off;
            if (ks < 4) off = (ks * 32 + hi * 16) ^ ((lq & 7) << 4);
            else        off = 128 + ((hi * 16) ^ ((lq & 1) << 4));
            bf16x8 kfrag = *(const bf16x8*)&kl[krow * KROWB + off];
            A = __builtin_amdgcn_mfma_f32_32x32x16_bf16(kfrag, qfragA[ks], A, 0, 0, 0);
            B = __builtin_amdgcn_mfma_f32_32x32x16_bf16(kfrag, qfragB[ks], B, 0, 0, 0);
        }
    };

    auto softmax = [&](f32x16& SA, f32x16& SB, bf16x8* pA, bf16x8* pB) {
        {
            float p[16];
            #pragma unroll
            for (int r = 0; r < 16; ++r) p[r] = __builtin_amdgcn_exp2f(SA[r]);
            U4 fa, fb;
            #pragma unroll
            for (int i = 0; i < 4; ++i) {
                fa.u[i] = pack2(p[2 * i],     p[2 * i + 1]);
                fb.u[i] = pack2(p[2 * i + 8], p[2 * i + 9]);
            }
            pA[0] = fa.v; pA[1] = fb.v;
            float s8[8];
            #pragma unroll
            for (int r = 0; r < 8; ++r) s8[r] = p[r] + p[r + 8];
            float s4[4];
            #pragma unroll
            for (int r = 0; r < 4; ++r) s4[r] = s8[r] + s8[r + 4];
            lA += (s4[0] + s4[1]) + (s4[2] + s4[3]);
        }
        {
            float p[16];
            #pragma unroll
            for (int r = 0; r < 16; ++r) p[r] = __builtin_amdgcn_exp2f(SB[r]);
            U4 fa, fb;
            #pragma unroll
            for (int i = 0; i < 4; ++i) {
                fa.u[i] = pack2(p[2 * i],     p[2 * i + 1]);
                fb.u[i] = pack2(p[2 * i + 8], p[2 * i + 9]);
            }
            pB[0] = fa.v; pB[1] = fb.v;
            float s8[8];
            #pragma unroll
            for (int r = 0; r < 8; ++r) s8[r] = p[r] + p[r + 8];
            float s4[4];
            #pragma unroll
            for (int r = 0; r < 4; ++r) s4[r] = s8[r] + s8[r + 4];
            lB += (s4[0] + s4[1]) + (s4[2] + s4[3]);
        }
    };

    auto pv = [&](int tt, bf16x8* pA, bf16x8* pB) {
        const char* vl = SMEM + 3 * KTILEB + (tt % 3) * VTILEB;
        __builtin_amdgcn_s_setprio(1);
        #pragma unroll
        for (int dt = 0; dt < 2; ++dt) {
            const int row = dt * 32 + lq;
            #pragma unroll
            for (int ks = 0; ks < 2; ++ks) {
                bf16x8 vfrag = *(const bf16x8*)&vl[sh * VHALFB + row * VSTRB + ks * 32 + hi * 16];
                oaccA[dt] = __builtin_amdgcn_mfma_f32_32x32x16_bf16(vfrag, pA[ks], oaccA[dt], 0, 0, 0);
                oaccB[dt] = __builtin_amdgcn_mfma_f32_32x32x16_bf16(vfrag, pB[ks], oaccB[dt], 0, 0, 0);
            }
        }
        __builtin_amdgcn_s_setprio(0);
    };

    // One barrier region per tile: stage(t+2) after barrier; QK(t+1) independent
    // of softmax(t); PV(t) closes. vmcnt(0) drains stage(t+1) issued one full
    // iteration earlier.
    auto step = [&](int t, f32x16& cA, f32x16& cB, f32x16& nA, f32x16& nB) {
        asm volatile("s_waitcnt vmcnt(0)" ::: "memory");
        __builtin_amdgcn_s_barrier();
        if (t + 2 < NT) stage(t + 2);
        bf16x8 pA[2], pB[2];
        if (t + 1 < NT) qk(t + 1, nA, nB);
        softmax(cA, cB, pA, pB);
        pv(t, pA, pB);
    };

    asm volatile("s_waitcnt vmcnt(0)" ::: "memory");
    __builtin_amdgcn_s_barrier();     // tiles 0 and 1 resident

    f32x16 s0A, s0B, s1A, s1B;
    qk(0, s0A, s0B);

    for (int t = 0; t < NT; t += 2) {
        step(t,     s0A, s0B, s1A, s1B);
        step(t + 1, s1A, s1B, s0A, s0B);
    }

    __syncthreads();   // all KV reads done; SMEM reusable for the combine

    // ---- combine s-half partials (intra-wave hi halves first) ----
    float lA2 = lA + __shfl_xor(lA, 32);
    float lB2 = lB + __shfl_xor(lB, 32);

    float* sO = (float*)SMEM;                 // 2 qp x 2 set x 64 lanes x 32 f32 = 32 KB
    float* sL = (float*)(SMEM + 32768);       // 2 qp x 2 set x 64 f32 = 1 KB
    if (sh == 1) {
        float* dst = sO + ((qp * 2 + 0) * 64 + lane) * 32;
        #pragma unroll
        for (int dt = 0; dt < 2; ++dt)
            #pragma unroll
            for (int r = 0; r < 16; ++r) dst[dt * 16 + r] = oaccA[dt][r];
        dst = sO + ((qp * 2 + 1) * 64 + lane) * 32;
        #pragma unroll
        for (int dt = 0; dt < 2; ++dt)
            #pragma unroll
            for (int r = 0; r < 16; ++r) dst[dt * 16 + r] = oaccB[dt][r];
        sL[(qp * 2 + 0) * 64 + lane] = lA2;
        sL[(qp * 2 + 1) * 64 + lane] = lB2;
    }
    __syncthreads();
    if (sh == 0) {
        // ---- q-set A ----
        {
            const float* src = sO + ((qp * 2 + 0) * 64 + lane) * 32;
            #pragma unroll
            for (int dt = 0; dt < 2; ++dt)
                #pragma unroll
                for (int r = 0; r < 16; ++r) oaccA[dt][r] += src[dt * 16 + r];
            const float lT = lA2 + sL[(qp * 2 + 0) * 64 + lane];
            const float invl = 1.0f / lT;
            float* ob = out + ((long)b * SEQ + qrowA) * (NHEADS * DFEAT) + h * DFEAT;
            #pragma unroll
            for (int dt = 0; dt < 2; ++dt) {
                #pragma unroll
                for (int g = 0; g < 4; ++g) {
                    const int d0 = dt * 32 + g * 8 + hi * 4;
                    float4 o;
                    o.x = oaccA[dt][4 * g + 0] * invl;
                    o.y = oaccA[dt][4 * g + 1] * invl;
                    o.z = oaccA[dt][4 * g + 2] * invl;
                    o.w = oaccA[dt][4 * g + 3] * invl;
                    *(float4*)(ob + d0) = o;
                }
            }
        }
        // ---- q-set B ----
        {
            const float* src = sO + ((qp * 2 + 1) * 64 + lane) * 32;
            #pragma unroll
            for (int dt = 0; dt < 2; ++dt)
                #pragma unroll
                for (int r = 0; r < 16; ++r) oaccB[dt][r] += src[dt * 16 + r];
            const float lT = lB2 + sL[(qp * 2 + 1) * 64 + lane];
            const float invl = 1.0f / lT;
            float* ob = out + ((long)b * SEQ + qrowB) * (NHEADS * DFEAT) + h * DFEAT;
            #pragma unroll
            for (int dt = 0; dt < 2; ++dt) {
                #pragma unroll
                for (int g = 0; g < 4; ++g) {
                    const int d0 = dt * 32 + g * 8 + hi * 4;
                    float4 o;
                    o.x = oaccB[dt][4 * g + 0] * invl;
                    o.y = oaccB[dt][4 * g + 1] * invl;
                    o.z = oaccB[dt][4 * g + 2] * invl;
                    o.w = oaccB[dt][4 * g + 3] * invl;
                    *(float4*)(ob + d0) = o;
                }
            }
        }
    }
}

// ---------------------------------------------------------------------------
// v1 fallback (round-1 kernel, proven) if ws is too small for pack buffers.
// ---------------------------------------------------------------------------
__global__ __launch_bounds__(256)
void stfa_v1(const float* __restrict__ qf, const float* __restrict__ kf,
             const float* __restrict__ qc, const float* __restrict__ kc,
             const float* __restrict__ vv, const float* __restrict__ alpha,
             float* __restrict__ out)
{
    __shared__ __align__(16) __hip_bfloat16 Klds[64 * 104];
    __shared__ __align__(16) __hip_bfloat16 Vlds[64 * 72];
    __shared__ __align__(16) __hip_bfloat16 Plds[4 * 16 * 72];

    const int tid  = threadIdx.x;
    const int wave = tid >> 6;
    const int lane = tid & 63;
    const int lr   = lane & 15;
    const int lg   = lane >> 4;

    const int blk   = blockIdx.x;
    const int qtile = blk & 31;
    const int h     = (blk >> 5) & 15;
    const int b     = blk >> 9;

    for (int i = tid; i < 64 * 104; i += 256) Klds[i] = __float2bfloat16(0.0f);

    const float a_h      = alpha[h];
    const float LOG2E    = 1.4426950408889634f;
    const float qf_scale = 0.125f * LOG2E;
    const float qc_scale = a_h * 0.35355339059327373f * LOG2E;

    const int qrow = qtile * 64 + wave * 16 + lr;
    const float* qf_p = qf + ((long)b * SEQ + qrow) * 1024 + h * 64;
    const float* qc_p = qc + ((long)b * SEQ + qrow) * 128 + h * 8;

    bf16x8 qfrag[3];
    #pragma unroll
    for (int st = 0; st < 2; ++st) {
        const float* p = qf_p + st * 32 + lg * 8;
        float4 f0 = *(const float4*)p;
        float4 f1 = *(const float4*)(p + 4);
        Bf8 q;
        q.e[0] = __float2bfloat16(f0.x * qf_scale); q.e[1] = __float2bfloat16(f0.y * qf_scale);
        q.e[2] = __float2bfloat16(f0.z * qf_scale); q.e[3] = __float2bfloat16(f0.w * qf_scale);
        q.e[4] = __float2bfloat16(f1.x * qf_scale); q.e[5] = __float2bfloat16(f1.y * qf_scale);
        q.e[6] = __float2bfloat16(f1.z * qf_scale); q.e[7] = __float2bfloat16(f1.w * qf_scale);
        qfrag[st] = q.v;
    }
    {
        Bf8 q;
        #pragma unroll
        for (int i = 0; i < 8; ++i) q.e[i] = __float2bfloat16(0.0f);
        if (lg == 0) {
            float4 c0 = *(const float4*)qc_p;
            float4 c1 = *(const float4*)(qc_p + 4);
            q.e[0] = __float2bfloat16(c0.x * qc_scale); q.e[1] = __float2bfloat16(c0.y * qc_scale);
            q.e[2] = __float2bfloat16(c0.z * qc_scale); q.e[3] = __float2bfloat16(c0.w * qc_scale);
            q.e[4] = __float2bfloat16(c1.x * qc_scale); q.e[5] = __float2bfloat16(c1.y * qc_scale);
            q.e[6] = __float2bfloat16(c1.z * qc_scale); q.e[7] = __float2bfloat16(c1.w * qc_scale);
        }
        qfrag[2] = q.v;
    }

    const float* kf_b = kf + (long)b * SEQ * 1024 + h * 64;
    const float* kc_b = kc + (long)b * SEQ * 128 + h * 8;
    const float* v_b  = vv + (long)b * SEQ * 1024 + h * 64;

    f32x4 oacc[4];
    #pragma unroll
    for (int ct = 0; ct < 4; ++ct) { oacc[ct][0]=0.f; oacc[ct][1]=0.f; oacc[ct][2]=0.f; oacc[ct][3]=0.f; }
    float m_r[4], l_r[4];
    #pragma unroll
    for (int j = 0; j < 4; ++j) { m_r[j] = -3.0e38f; l_r[j] = 0.f; }

    __syncthreads();

    for (int s0 = 0; s0 < SEQ; s0 += 64) {
        {
            const int srow = tid >> 2, ch = tid & 3;
            const float* p = kf_b + (long)(s0 + srow) * 1024 + ch * 16;
            float4 f0 = ((const float4*)p)[0];
            float4 f1 = ((const float4*)p)[1];
            float4 f2 = ((const float4*)p)[2];
            float4 f3 = ((const float4*)p)[3];
            Bf8 w0, w1;
            w0.e[0]=__float2bfloat16(f0.x); w0.e[1]=__float2bfloat16(f0.y);
            w0.e[2]=__float2bfloat16(f0.z); w0.e[3]=__float2bfloat16(f0.w);
            w0.e[4]=__float2bfloat16(f1.x); w0.e[5]=__float2bfloat16(f1.y);
            w0.e[6]=__float2bfloat16(f1.z); w0.e[7]=__float2bfloat16(f1.w);
            w1.e[0]=__float2bfloat16(f2.x); w1.e[1]=__float2bfloat16(f2.y);
            w1.e[2]=__float2bfloat16(f2.z); w1.e[3]=__float2bfloat16(f2.w);
            w1.e[4]=__float2bfloat16(f3.x); w1.e[5]=__float2bfloat16(f3.y);
            w1.e[6]=__float2bfloat16(f3.z); w1.e[7]=__float2bfloat16(f3.w);
            *(bf16x8*)&Klds[srow * 104 + ch * 16]     = w0.v;
            *(bf16x8*)&Klds[srow * 104 + ch * 16 + 8] = w1.v;
        }
        {
            const int srow = tid >> 2, cp = (tid & 3) * 2;
            const float* p = kc_b + (long)(s0 + srow) * 128 + cp;
            float2 c = *(const float2*)p;
            Klds[srow * 104 + 64 + cp]     = __float2bfloat16(c.x);
            Klds[srow * 104 + 64 + cp + 1] = __float2bfloat16(c.y);
        }
        {
            const int srow = tid & 63, d0 = (tid >> 6) * 16;
            const float* p = v_b + (long)(s0 + srow) * 1024 + d0;
            #pragma unroll
            for (int c4 = 0; c4 < 4; ++c4) {
                float4 f = ((const float4*)p)[c4];
                Vlds[(d0 + c4 * 4 + 0) * 72 + srow] = __float2bfloat16(f.x);
                Vlds[(d0 + c4 * 4 + 1) * 72 + srow] = __float2bfloat16(f.y);
                Vlds[(d0 + c4 * 4 + 2) * 72 + srow] = __float2bfloat16(f.z);
                Vlds[(d0 + c4 * 4 + 3) * 72 + srow] = __float2bfloat16(f.w);
            }
        }
        __syncthreads();

        f32x4 sacc[4];
        #pragma unroll
        for (int ct = 0; ct < 4; ++ct) { sacc[ct][0]=0.f; sacc[ct][1]=0.f; sacc[ct][2]=0.f; sacc[ct][3]=0.f; }
        #pragma unroll
        for (int ct = 0; ct < 4; ++ct) {
            #pragma unroll
            for (int st = 0; st < 3; ++st) {
                bf16x8 kfrag = *(const bf16x8*)&Klds[(ct * 16 + lr) * 104 + st * 32 + lg * 8];
                sacc[ct] = __builtin_amdgcn_mfma_f32_16x16x32_bf16(qfrag[st], kfrag, sacc[ct], 0, 0, 0);
            }
        }

        float rs[4];
        #pragma unroll
        for (int j = 0; j < 4; ++j) {
            float mx = fmaxf(fmaxf(sacc[0][j], sacc[1][j]), fmaxf(sacc[2][j], sacc[3][j]));
            mx = fmaxf(mx, __shfl_xor(mx, 1));
            mx = fmaxf(mx, __shfl_xor(mx, 2));
            mx = fmaxf(mx, __shfl_xor(mx, 4));
            mx = fmaxf(mx, __shfl_xor(mx, 8));
            float nm = fmaxf(m_r[j], mx);
            rs[j] = __builtin_amdgcn_exp2f(m_r[j] - nm);
            m_r[j] = nm;
        }
        __hip_bfloat16* myP = Plds + wave * 16 * 72;
        #pragma unroll
        for (int j = 0; j < 4; ++j) {
            float p0 = __builtin_amdgcn_exp2f(sacc[0][j] - m_r[j]);
            float p1 = __builtin_amdgcn_exp2f(sacc[1][j] - m_r[j]);
            float p2 = __builtin_amdgcn_exp2f(sacc[2][j] - m_r[j]);
            float p3 = __builtin_amdgcn_exp2f(sacc[3][j] - m_r[j]);
            const int r = lg * 4 + j;
            myP[r * 72 +  0 + lr] = __float2bfloat16(p0);
            myP[r * 72 + 16 + lr] = __float2bfloat16(p1);
            myP[r * 72 + 32 + lr] = __float2bfloat16(p2);
            myP[r * 72 + 48 + lr] = __float2bfloat16(p3);
            float sum = p0 + p1 + p2 + p3;
            sum += __shfl_xor(sum, 1);
            sum += __shfl_xor(sum, 2);
            sum += __shfl_xor(sum, 4);
            sum += __shfl_xor(sum, 8);
            l_r[j] = l_r[j] * rs[j] + sum;
            oacc[0][j] *= rs[j]; oacc[1][j] *= rs[j];
            oacc[2][j] *= rs[j]; oacc[3][j] *= rs[j];
        }

        #pragma unroll
        for (int kk = 0; kk < 2; ++kk) {
            bf16x8 pfrag = *(const bf16x8*)&myP[lr * 72 + kk * 32 + lg * 8];
            #pragma unroll
            for (int ct = 0; ct < 4; ++ct) {
                bf16x8 vfrag = *(const bf16x8*)&Vlds[(ct * 16 + lr) * 72 + kk * 32 + lg * 8];
                oacc[ct] = __builtin_amdgcn_mfma_f32_16x16x32_bf16(pfrag, vfrag, oacc[ct], 0, 0, 0);
            }
        }
        __syncthreads();
    }

    #pragma unroll
    for (int j = 0; j < 4; ++j) {
        const float invl = 1.0f / l_r[j];
        const int q = qtile * 64 + wave * 16 + lg * 4 + j;
        float* op = out + ((long)b * SEQ + q) * 1024 + h * 64;
        op[ 0 + lr] = oacc[0][j] * invl;
        op[16 + lr] = oacc[1][j] * invl;
        op[32 + lr] = oacc[2][j] * invl;
        op[48 + lr] = oacc[3][j] * invl;
    }
}

extern "C" void kernel_launch(void* const* d_in, const int* in_sizes, int n_in,
                              void* d_out, int out_size, void* d_ws, size_t ws_size,
                              hipStream_t stream) {
    const float* qf    = (const float*)d_in[0];
    const float* kf    = (const float*)d_in[1];
    const float* qc    = (const float*)d_in[2];
    const float* kc    = (const float*)d_in[3];
    const float* vv    = (const float*)d_in[4];
    const float* alpha = (const float*)d_in[5];
    float* out = (float*)d_out;

    const int B = 2;
    if (ws_size >= KP_BYTES + VT_BYTES) {
        char* kp = (char*)d_ws;
        char* vt = (char*)d_ws + KP_BYTES;
        pack_kv<<<2 * B * NHEADS * NT, 256, 0, stream>>>(kf, kc, vv, kp, vt);
        stfa_v10<<<B * NHEADS * (SEQ / QBLK), 256, 0, stream>>>(qf, qc, alpha, kp, vt, out);
    } else {
        stfa_v1<<<B * NHEADS * (SEQ / 64), 256, 0, stream>>>(qf, kf, qc, kc, vv, alpha, out);
    }
}

// Round 12
// 65.284 us; speedup vs baseline: 1.3385x; 1.0222x over previous
//
#include <hip/hip_runtime.h>
#include <hip/hip_bf16.h>

typedef __bf16 bf16_t;
typedef bf16_t bf16x8 __attribute__((ext_vector_type(8)));
typedef float f32x4 __attribute__((ext_vector_type(4)));
typedef float f32x16 __attribute__((ext_vector_type(16)));

#define NHEADS 16
#define DFEAT 64
#define DCOORD 8
#define SEQ 2048
#define KVBLK 64
#define NT (SEQ / KVBLK)
#define QBLK 128                       // 4 waves = (qpair 0/1) x (s-half 0/1); 64 q per wave
#define KCOLS 80                       // K' cols: 64 feat + 8 coord + 8 zero
#define KROWB (KCOLS * 2)              // 160 B row stride
#define KTILEB (KVBLK * KROWB)         // 10240 B per K tile
#define VSTRB 80                       // V^T half-tile row stride (bytes): 32 s + 8 pad
#define VHALFB (DFEAT * VSTRB)         // 5120 B per s-half
#define VTILEB (2 * VHALFB)            // 10240 B per V tile (== KTILEB)

#define KP_BYTES ((size_t)32 * NT * KTILEB)   // 10,485,760
#define VT_BYTES ((size_t)32 * NT * VTILEB)   // 10,485,760

union Bf8 { bf16x8 v; __hip_bfloat16 e[8]; };
union U4  { unsigned u[4]; bf16x8 v; };

static __device__ inline unsigned pack2(float a, float b) {
    union { __hip_bfloat16 h[2]; unsigned u; } x;
    x.h[0] = __float2bfloat16(a); x.h[1] = __float2bfloat16(b);
    return x.u;
}

// ---------------------------------------------------------------------------
// Merged pre-pass (v9-verified, unchanged): blocks [0,1024) pack K' tiles,
// [1024,2048) pack V^T tiles.
// ---------------------------------------------------------------------------
__global__ __launch_bounds__(256)
void pack_kv(const float* __restrict__ kf, const float* __restrict__ kc,
             const float* __restrict__ v,
             char* __restrict__ kp, char* __restrict__ vt)
{
    __shared__ __align__(16) char tile[KTILEB];   // 10240 B
    const int bid = blockIdx.x;
    const int tid = threadIdx.x;

    if (bid < 1024) {
        // ---------------- K' pack ----------------
        const int blk = bid;               // [bh][t]
        const int t  = blk & (NT - 1);
        const int bh = blk >> 5;
        const int b = bh >> 4, h = bh & 15;
        #pragma unroll
        for (int it = 0; it < 2; ++it) {
            const int c = tid + it * 256;      // 320 chunk-pairs (row, cc)
            if (c < 320) {
                const int row = c / 5, cc = c - row * 5;
                const int s = t * KVBLK + row;
                float vv[16];
                if (cc < 4) {
                    const float* p = kf + ((long)b * SEQ + s) * (NHEADS * DFEAT) + h * DFEAT + cc * 16;
                    #pragma unroll
                    for (int i = 0; i < 4; ++i) {
                        float4 f = ((const float4*)p)[i];
                        vv[4*i+0]=f.x; vv[4*i+1]=f.y; vv[4*i+2]=f.z; vv[4*i+3]=f.w;
                    }
                } else {
                    const float* p = kc + ((long)b * SEQ + s) * (NHEADS * DCOORD) + h * DCOORD;
                    float4 f0 = ((const float4*)p)[0];
                    float4 f1 = ((const float4*)p)[1];
                    vv[0]=f0.x; vv[1]=f0.y; vv[2]=f0.z; vv[3]=f0.w;
                    vv[4]=f1.x; vv[5]=f1.y; vv[6]=f1.z; vv[7]=f1.w;
                    #pragma unroll
                    for (int i = 8; i < 16; ++i) vv[i] = 0.f;
                }
                Bf8 w0, w1;
                #pragma unroll
                for (int i = 0; i < 8; ++i) {
                    w0.e[i] = __float2bfloat16(vv[i]);
                    w1.e[i] = __float2bfloat16(vv[i + 8]);
                }
                if (cc < 4) {
                    const int key = (row & 7) << 4;
                    const int base = cc * 32;
                    *(bf16x8*)&tile[row * KROWB + ((base)      ^ key)] = w0.v;
                    *(bf16x8*)&tile[row * KROWB + ((base + 16) ^ key)] = w1.v;
                } else {
                    const int key = (row & 1) << 4;
                    *(bf16x8*)&tile[row * KROWB + 128 + ((0)  ^ key)] = w0.v;
                    *(bf16x8*)&tile[row * KROWB + 128 + ((16) ^ key)] = w1.v;
                }
            }
        }
        __syncthreads();
        const bf16x8* ti = (const bf16x8*)tile;
        bf16x8* o = (bf16x8*)(kp + (long)blk * KTILEB);
        #pragma unroll
        for (int j = 0; j < 3; ++j) {
            const int i = tid + 256 * j;
            if (i < 640) o[i] = ti[i];
        }
    } else {
        // ---------------- V^T pack ----------------
        const int blk = bid - 1024;        // [bh][t]
        const int t  = blk & (NT - 1);
        const int bh = blk >> 5;
        const int b = bh >> 4, h = bh & 15;
        const int s = tid >> 2, c = tid & 3;
        const int sh = s >> 5, sl = s & 31;
        const int slot = (sl & ~12) | ((sl & 4) << 1) | ((sl & 8) >> 1);  // swap bits 2,3
        const float* src = v + ((long)b * SEQ + t * KVBLK + s) * (NHEADS * DFEAT) + h * DFEAT;
        __hip_bfloat16* vtile = (__hip_bfloat16*)tile;
        #pragma unroll
        for (int c4 = 0; c4 < 4; ++c4) {
            float4 f = ((const float4*)src)[c4 * 4 + c];
            float vals[4] = {f.x, f.y, f.z, f.w};
            #pragma unroll
            for (int ii = 0; ii < 4; ++ii) {
                const int dd = c4 * 16 + c * 4 + ii;
                const int byte = sh * VHALFB + dd * VSTRB + slot * 2;
                vtile[byte >> 1] = __float2bfloat16(vals[ii]);
            }
        }
        __syncthreads();
        const bf16x8* ti = (const bf16x8*)tile;
        bf16x8* o = (bf16x8*)(vt + (long)blk * (long)VTILEB);
        #pragma unroll
        for (int j = 0; j < 3; ++j) {
            const int i = tid + 256 * j;
            if (i < 640) o[i] = ti[i];
        }
    }
}

// ---------------------------------------------------------------------------
// Main kernel v11: v9 geometry (s-split x q-reuse) with ALL per-tile address
// arithmetic hoisted out of the loop. KTILEB==VTILEB==10240 so buffer parity
// is a compile-time ds_read immediate after manual unroll-by-2; stage uses 5
// precomputed per-wave voffsets + one uniform pointer bump per tile.
// ---------------------------------------------------------------------------
__global__ __launch_bounds__(256, 2)
void stfa_v11(const float* __restrict__ qf, const float* __restrict__ qc,
              const float* __restrict__ alpha,
              const char* __restrict__ kp, const char* __restrict__ vt,
              float* __restrict__ out)
{
    __shared__ __align__(16) char SMEM[2 * KTILEB + 2 * VTILEB];   // 40960 B
    // layout: [K buf0 | K buf1 | V buf0 | V buf1], each 10240 B

    const int tid  = threadIdx.x;
    const int wave = tid >> 6;
    const int lane = tid & 63;
    const int lq   = lane & 31;
    const int hi   = lane >> 5;
    const int qp   = wave >> 1;
    const int sh   = wave & 1;

    const int dd    = blockIdx.x;     // [qtile(4b)][bh(5b)]: same-bh -> same XCD
    const int bh    = dd & 31;
    const int qtile = dd >> 5;
    const int b = bh >> 4, h = bh & 15;

    const float a_h      = alpha[h];
    const float LOG2E    = 1.4426950408889634f;
    const float qf_scale = 0.125f * LOG2E;
    const float qc_scale = a_h * 0.35355339059327373f * LOG2E;

    const char* kp_bh = kp + (long)bh * NT * KTILEB;

    // ---- hoisted stage addressing: chunk c = wave + 4j (j=0..4), c<10 -> K, else V.
    // V region sits exactly KP_BYTES after K region (identical bh/tile strides).
    long voff[5];
    #pragma unroll
    for (int j = 0; j < 5; ++j) {
        const int c = wave + 4 * j;
        voff[j] = (c < 10) ? ((long)c * 1024 + lane * 16)
                           : ((long)KP_BYTES + (long)(c - 10) * 1024 + lane * 16);
    }
    int ldsoff[5];
    #pragma unroll
    for (int j = 0; j < 5; ++j) {
        const int c = wave + 4 * j;
        ldsoff[j] = (c < 10) ? c * 1024 : 2 * KTILEB + (c - 10) * 1024;
    }

    // BB: 0 for buf0 tiles (even t), 10240 for buf1 tiles (odd t) — literal.
    auto stage = [&](const char* kg_run, const int BB) {
        #pragma unroll
        for (int j = 0; j < 5; ++j) {
            __builtin_amdgcn_global_load_lds(
                (const __attribute__((address_space(1))) void*)(kg_run + voff[j]),
                (__attribute__((address_space(3))) void*)(SMEM + ldsoff[j] + BB), 16, 0, 0);
        }
    };

    // ---- hoisted LDS read offsets (byte), buffer-relative ----
    const int krow = sh * 32 + lq;
    int qkaddr[5];
    #pragma unroll
    for (int ks = 0; ks < 5; ++ks) {
        int off;
        if (ks < 4) off = (ks * 32 + hi * 16) ^ ((lq & 7) << 4);
        else        off = 128 + ((hi * 16) ^ ((lq & 1) << 4));
        qkaddr[ks] = krow * KROWB + off;
    }
    int pvaddr[4];
    #pragma unroll
    for (int dt = 0; dt < 2; ++dt)
        #pragma unroll
        for (int ks = 0; ks < 2; ++ks)
            pvaddr[dt * 2 + ks] = sh * VHALFB + (dt * 32 + lq) * VSTRB + ks * 32 + hi * 16;

    // ---- Q' fragments for both q-sets (A: qp*64+lq, B: +32) ----
    const int qrowA = qtile * QBLK + qp * 64 + lq;
    const int qrowB = qrowA + 32;

    bf16x8 qfragA[5], qfragB[5];
    #pragma unroll
    for (int set = 0; set < 2; ++set) {
        const int qrow = set ? qrowB : qrowA;
        const float* qfp = qf + ((long)b * SEQ + qrow) * (NHEADS * DFEAT) + h * DFEAT;
        const float* qcp = qc + ((long)b * SEQ + qrow) * (NHEADS * DCOORD) + h * DCOORD;
        #pragma unroll
        for (int ks = 0; ks < 4; ++ks) {
            const float* p = qfp + ks * 16 + hi * 8;
            float4 f0 = *(const float4*)p;
            float4 f1 = *(const float4*)(p + 4);
            Bf8 q;
        q.e[0] = __float2bfloat16(f0.x * qf_scale); q.e[1] = __float2bfloat16(f0.y * qf_scale);
        q.e[2] = __float2bfloat16(f0.z * qf_scale); q.e[3] = __float2bfloat16(f0.w * qf_scale);
        q.e[4] = __float2bfloat16(f1.x * qf_scale); q.e[5] = __float2bfloat16(f1.y * qf_scale);
        q.e[6] = __float2bfloat16(f1.z * qf_scale); q.e[7] = __float2bfloat16(f1.w * qf_scale);
            if (set) qfragB[ks] = q.v; else qfragA[ks] = q.v;
        }
        Bf8 q;
        #pragma unroll
        for (int i = 0; i < 8; ++i) q.e[i] = __float2bfloat16(0.0f);
        if (hi == 0) {
            float4 c0 = *(const float4*)qcp;
            float4 c1 = *(const float4*)(qcp + 4);
            q.e[0] = __float2bfloat16(c0.x * qc_scale); q.e[1] = __float2bfloat16(c0.y * qc_scale);
            q.e[2] = __float2bfloat16(c0.z * qc_scale); q.e[3] = __float2bfloat16(c0.w * qc_scale);
            q.e[4] = __float2bfloat16(c1.x * qc_scale); q.e[5] = __float2bfloat16(c1.y * qc_scale);
            q.e[6] = __float2bfloat16(c1.z * qc_scale); q.e[7] = __float2bfloat16(c1.w * qc_scale);
        }
        if (set) qfragB[4] = q.v; else qfragA[4] = q.v;
    }

    f32x16 oaccA[2], oaccB[2];
    #pragma unroll
    for (int dt = 0; dt < 2; ++dt)
        #pragma unroll
        for (int r = 0; r < 16; ++r) { oaccA[dt][r] = 0.f; oaccB[dt][r] = 0.f; }
    float lA = 0.f, lB = 0.f;

    // Per-tile body; KB/VB are literals per unrolled parity copy.
    auto body = [&](const int KB, const int VB) {
        f32x16 sA, sB;
        #pragma unroll
        for (int r = 0; r < 16; ++r) { sA[r] = 0.f; sB[r] = 0.f; }
        __builtin_amdgcn_s_setprio(1);
        #pragma unroll
        for (int ks = 0; ks < 5; ++ks) {
            bf16x8 kfrag = *(const bf16x8*)&SMEM[KB + qkaddr[ks]];
            sA = __builtin_amdgcn_mfma_f32_32x32x16_bf16(kfrag, qfragA[ks], sA, 0, 0, 0);
            sB = __builtin_amdgcn_mfma_f32_32x32x16_bf16(kfrag, qfragB[ks], sB, 0, 0, 0);
        }
        __builtin_amdgcn_s_setprio(0);

        bf16x8 pA[2], pB[2];
        {
            float p[16];
            #pragma unroll
            for (int r = 0; r < 16; ++r) p[r] = __builtin_amdgcn_exp2f(sA[r]);
            U4 fa, fb;
            #pragma unroll
            for (int i = 0; i < 4; ++i) {
                fa.u[i] = pack2(p[2 * i],     p[2 * i + 1]);
                fb.u[i] = pack2(p[2 * i + 8], p[2 * i + 9]);
            }
            pA[0] = fa.v; pA[1] = fb.v;
            float s8[8];
            #pragma unroll
            for (int r = 0; r < 8; ++r) s8[r] = p[r] + p[r + 8];
            float s4[4];
            #pragma unroll
            for (int r = 0; r < 4; ++r) s4[r] = s8[r] + s8[r + 4];
            lA += (s4[0] + s4[1]) + (s4[2] + s4[3]);
        }
        {
            float p[16];
            #pragma unroll
            for (int r = 0; r < 16; ++r) p[r] = __builtin_amdgcn_exp2f(sB[r]);
            U4 fa, fb;
            #pragma unroll
            for (int i = 0; i < 4; ++i) {
                fa.u[i] = pack2(p[2 * i],     p[2 * i + 1]);
                fb.u[i] = pack2(p[2 * i + 8], p[2 * i + 9]);
            }
            pB[0] = fa.v; pB[1] = fb.v;
            float s8[8];
            #pragma unroll
            for (int r = 0; r < 8; ++r) s8[r] = p[r] + p[r + 8];
            float s4[4];
            #pragma unroll
            for (int r = 0; r < 4; ++r) s4[r] = s8[r] + s8[r + 4];
            lB += (s4[0] + s4[1]) + (s4[2] + s4[3]);
        }

        __builtin_amdgcn_s_setprio(1);
        #pragma unroll
        for (int dt = 0; dt < 2; ++dt) {
            #pragma unroll
            for (int ks = 0; ks < 2; ++ks) {
                bf16x8 vfrag = *(const bf16x8*)&SMEM[VB + pvaddr[dt * 2 + ks]];
                oaccA[dt] = __builtin_amdgcn_mfma_f32_32x32x16_bf16(vfrag, pA[ks], oaccA[dt], 0, 0, 0);
                oaccB[dt] = __builtin_amdgcn_mfma_f32_32x32x16_bf16(vfrag, pB[ks], oaccB[dt], 0, 0, 0);
            }
        }
        __builtin_amdgcn_s_setprio(0);
    };

    // ---- prologue: stage tile 0 into buf0 ----
    const char* kg_run = kp_bh;      // points at the tile being staged
    stage(kg_run, 0);
    kg_run += KTILEB;
    __syncthreads();                 // tile 0 resident

    // ---- main loop, unrolled by 2 (NT = 32, even) ----
    for (int t = 0; t < NT; t += 2) {
        // even tile t: compute from buf0; stage t+1 into buf1
        stage(kg_run, KTILEB);
        kg_run += KTILEB;
        body(0, 2 * KTILEB);
        __syncthreads();
        // odd tile t+1: compute from buf1; stage t+2 into buf0
        if (t + 2 < NT) { stage(kg_run, 0); kg_run += KTILEB; }
        body(KTILEB, 2 * KTILEB + VTILEB);
        __syncthreads();
    }

    // ---- combine s-half partials (intra-wave hi halves first) ----
    float lA2 = lA + __shfl_xor(lA, 32);
    float lB2 = lB + __shfl_xor(lB, 32);

    float* sO = (float*)SMEM;                 // 2 qp x 2 set x 64 lanes x 32 f32 = 32 KB
    float* sL = (float*)(SMEM + 32768);       // 2 qp x 2 set x 64 f32 = 1 KB
    if (sh == 1) {
        float* dst = sO + ((qp * 2 + 0) * 64 + lane) * 32;
        #pragma unroll
        for (int dt = 0; dt < 2; ++dt)
            #pragma unroll
            for (int r = 0; r < 16; ++r) dst[dt * 16 + r] = oaccA[dt][r];
        dst = sO + ((qp * 2 + 1) * 64 + lane) * 32;
        #pragma unroll
        for (int dt = 0; dt < 2; ++dt)
            #pragma unroll
            for (int r = 0; r < 16; ++r) dst[dt * 16 + r] = oaccB[dt][r];
        sL[(qp * 2 + 0) * 64 + lane] = lA2;
        sL[(qp * 2 + 1) * 64 + lane] = lB2;
    }
    __syncthreads();
    if (sh == 0) {
        {
            const float* src = sO + ((qp * 2 + 0) * 64 + lane) * 32;
            #pragma unroll
            for (int dt = 0; dt < 2; ++dt)
                #pragma unroll
                for (int r = 0; r < 16; ++r) oaccA[dt][r] += src[dt * 16 + r];
            const float lT = lA2 + sL[(qp * 2 + 0) * 64 + lane];
            const float invl = 1.0f / lT;
            float* ob = out + ((long)b * SEQ + qrowA) * (NHEADS * DFEAT) + h * DFEAT;
            #pragma unroll
            for (int dt = 0; dt < 2; ++dt) {
                #pragma unroll
                for (int g = 0; g < 4; ++g) {
                    const int d0 = dt * 32 + g * 8 + hi * 4;
                    float4 o;
                    o.x = oaccA[dt][4 * g + 0] * invl;
                    o.y = oaccA[dt][4 * g + 1] * invl;
                    o.z = oaccA[dt][4 * g + 2] * invl;
                    o.w = oaccA[dt][4 * g + 3] * invl;
                    *(float4*)(ob + d0) = o;
                }
            }
        }
        {
            const float* src = sO + ((qp * 2 + 1) * 64 + lane) * 32;
            #pragma unroll
            for (int dt = 0; dt < 2; ++dt)
                #pragma unroll
                for (int r = 0; r < 16; ++r) oaccB[dt][r] += src[dt * 16 + r];
            const float lT = lB2 + sL[(qp * 2 + 1) * 64 + lane];
            const float invl = 1.0f / lT;
            float* ob = out + ((long)b * SEQ + qrowB) * (NHEADS * DFEAT) + h * DFEAT;
            #pragma unroll
            for (int dt = 0; dt < 2; ++dt) {
                #pragma unroll
                for (int g = 0; g < 4; ++g) {
                    const int d0 = dt * 32 + g * 8 + hi * 4;
                    float4 o;
                    o.x = oaccB[dt][4 * g + 0] * invl;
                    o.y = oaccB[dt][4 * g + 1] * invl;
                    o.z = oaccB[dt][4 * g + 2] * invl;
                    o.w = oaccB[dt][4 * g + 3] * invl;
                    *(float4*)(ob + d0) = o;
                }
            }
        }
    }
}

// ---------------------------------------------------------------------------
// v1 fallback (round-1 kernel, proven) if ws is too small for pack buffers.
// ---------------------------------------------------------------------------
__global__ __launch_bounds__(256)
void stfa_v1(const float* __restrict__ qf, const float* __restrict__ kf,
             const float* __restrict__ qc, const float* __restrict__ kc,
             const float* __restrict__ vv, const float* __restrict__ alpha,
             float* __restrict__ out)
{
    __shared__ __align__(16) __hip_bfloat16 Klds[64 * 104];
    __shared__ __align__(16) __hip_bfloat16 Vlds[64 * 72];
    __shared__ __align__(16) __hip_bfloat16 Plds[4 * 16 * 72];

    const int tid  = threadIdx.x;
    const int wave = tid >> 6;
    const int lane = tid & 63;
    const int lr   = lane & 15;
    const int lg   = lane >> 4;

    const int blk   = blockIdx.x;
    const int qtile = blk & 31;
    const int h     = (blk >> 5) & 15;
    const int b     = blk >> 9;

    for (int i = tid; i < 64 * 104; i += 256) Klds[i] = __float2bfloat16(0.0f);

    const float a_h      = alpha[h];
    const float LOG2E    = 1.4426950408889634f;
    const float qf_scale = 0.125f * LOG2E;
    const float qc_scale = a_h * 0.35355339059327373f * LOG2E;

    const int qrow = qtile * 64 + wave * 16 + lr;
    const float* qf_p = qf + ((long)b * SEQ + qrow) * 1024 + h * 64;
    const float* qc_p = qc + ((long)b * SEQ + qrow) * 128 + h * 8;

    bf16x8 qfrag[3];
    #pragma unroll
    for (int st = 0; st < 2; ++st) {
        const float* p = qf_p + st * 32 + lg * 8;
        float4 f0 = *(const float4*)p;
        float4 f1 = *(const float4*)(p + 4);
        Bf8 q;
        q.e[0] = __float2bfloat16(f0.x * qf_scale); q.e[1] = __float2bfloat16(f0.y * qf_scale);
        q.e[2] = __float2bfloat16(f0.z * qf_scale); q.e[3] = __float2bfloat16(f0.w * qf_scale);
        q.e[4] = __float2bfloat16(f1.x * qf_scale); q.e[5] = __float2bfloat16(f1.y * qf_scale);
        q.e[6] = __float2bfloat16(f1.z * qf_scale); q.e[7] = __float2bfloat16(f1.w * qf_scale);
        qfrag[st] = q.v;
    }
    {
        Bf8 q;
        #pragma unroll
        for (int i = 0; i < 8; ++i) q.e[i] = __float2bfloat16(0.0f);
        if (lg == 0) {
            float4 c0 = *(const float4*)qc_p;
            float4 c1 = *(const float4*)(qc_p + 4);
            q.e[0] = __float2bfloat16(c0.x * qc_scale); q.e[1] = __float2bfloat16(c0.y * qc_scale);
            q.e[2] = __float2bfloat16(c0.z * qc_scale); q.e[3] = __float2bfloat16(c0.w * qc_scale);
            q.e[4] = __float2bfloat16(c1.x * qc_scale); q.e[5] = __float2bfloat16(c1.y * qc_scale);
            q.e[6] = __float2bfloat16(c1.z * qc_scale); q.e[7] = __float2bfloat16(c1.w * qc_scale);
        }
        qfrag[2] = q.v;
    }

    const float* kf_b = kf + (long)b * SEQ * 1024 + h * 64;
    const float* kc_b = kc + (long)b * SEQ * 128 + h * 8;
    const float* v_b  = vv + (long)b * SEQ * 1024 + h * 64;

    f32x4 oacc[4];
    #pragma unroll
    for (int ct = 0; ct < 4; ++ct) { oacc[ct][0]=0.f; oacc[ct][1]=0.f; oacc[ct][2]=0.f; oacc[ct][3]=0.f; }
    float m_r[4], l_r[4];
    #pragma unroll
    for (int j = 0; j < 4; ++j) { m_r[j] = -3.0e38f; l_r[j] = 0.f; }

    __syncthreads();

    for (int s0 = 0; s0 < SEQ; s0 += 64) {
        {
            const int srow = tid >> 2, ch = tid & 3;
            const float* p = kf_b + (long)(s0 + srow) * 1024 + ch * 16;
            float4 f0 = ((const float4*)p)[0];
            float4 f1 = ((const float4*)p)[1];
            float4 f2 = ((const float4*)p)[2];
            float4 f3 = ((const float4*)p)[3];
            Bf8 w0, w1;
            w0.e[0]=__float2bfloat16(f0.x); w0.e[1]=__float2bfloat16(f0.y);
            w0.e[2]=__float2bfloat16(f0.z); w0.e[3]=__float2bfloat16(f0.w);
            w0.e[4]=__float2bfloat16(f1.x); w0.e[5]=__float2bfloat16(f1.y);
            w0.e[6]=__float2bfloat16(f1.z); w0.e[7]=__float2bfloat16(f1.w);
            w1.e[0]=__float2bfloat16(f2.x); w1.e[1]=__float2bfloat16(f2.y);
            w1.e[2]=__float2bfloat16(f2.z); w1.e[3]=__float2bfloat16(f2.w);
            w1.e[4]=__float2bfloat16(f3.x); w1.e[5]=__float2bfloat16(f3.y);
            w1.e[6]=__float2bfloat16(f3.z); w1.e[7]=__float2bfloat16(f3.w);
            *(bf16x8*)&Klds[srow * 104 + ch * 16]     = w0.v;
            *(bf16x8*)&Klds[srow * 104 + ch * 16 + 8] = w1.v;
        }
        {
            const int srow = tid >> 2, cp = (tid & 3) * 2;
            const float* p = kc_b + (long)(s0 + srow) * 128 + cp;
            float2 c = *(const float2*)p;
            Klds[srow * 104 + 64 + cp]     = __float2bfloat16(c.x);
            Klds[srow * 104 + 64 + cp + 1] = __float2bfloat16(c.y);
        }
        {
            const int srow = tid & 63, d0 = (tid >> 6) * 16;
            const float* p = v_b + (long)(s0 + srow) * 1024 + d0;
            #pragma unroll
            for (int c4 = 0; c4 < 4; ++c4) {
                float4 f = ((const float4*)p)[c4];
                Vlds[(d0 + c4 * 4 + 0) * 72 + srow] = __float2bfloat16(f.x);
                Vlds[(d0 + c4 * 4 + 1) * 72 + srow] = __float2bfloat16(f.y);
                Vlds[(d0 + c4 * 4 + 2) * 72 + srow] = __float2bfloat16(f.z);
                Vlds[(d0 + c4 * 4 + 3) * 72 + srow] = __float2bfloat16(f.w);
            }
        }
        __syncthreads();

        f32x4 sacc[4];
        #pragma unroll
        for (int ct = 0; ct < 4; ++ct) { sacc[ct][0]=0.f; sacc[ct][1]=0.f; sacc[ct][2]=0.f; sacc[ct][3]=0.f; }
        #pragma unroll
        for (int ct = 0; ct < 4; ++ct) {
            #pragma unroll
            for (int st = 0; st < 3; ++st) {
                bf16x8 kfrag = *(const bf16x8*)&Klds[(ct * 16 + lr) * 104 + st * 32 + lg * 8];
                sacc[ct] = __builtin_amdgcn_mfma_f32_16x16x32_bf16(qfrag[st], kfrag, sacc[ct], 0, 0, 0);
            }
        }

        float rs[4];
        #pragma unroll
        for (int j = 0; j < 4; ++j) {
            float mx = fmaxf(fmaxf(sacc[0][j], sacc[1][j]), fmaxf(sacc[2][j], sacc[3][j]));
            mx = fmaxf(mx, __shfl_xor(mx, 1));
            mx = fmaxf(mx, __shfl_xor(mx, 2));
            mx = fmaxf(mx, __shfl_xor(mx, 4));
            mx = fmaxf(mx, __shfl_xor(mx, 8));
            float nm = fmaxf(m_r[j], mx);
            rs[j] = __builtin_amdgcn_exp2f(m_r[j] - nm);
            m_r[j] = nm;
        }
        __hip_bfloat16* myP = Plds + wave * 16 * 72;
        #pragma unroll
        for (int j = 0; j < 4; ++j) {
            float p0 = __builtin_amdgcn_exp2f(sacc[0][j] - m_r[j]);
            float p1 = __builtin_amdgcn_exp2f(sacc[1][j] - m_r[j]);
            float p2 = __builtin_amdgcn_exp2f(sacc[2][j] - m_r[j]);
            float p3 = __builtin_amdgcn_exp2f(sacc[3][j] - m_r[j]);
            const int r = lg * 4 + j;
            myP[r * 72 +  0 + lr] = __float2bfloat16(p0);
            myP[r * 72 + 16 + lr] = __float2bfloat16(p1);
            myP[r * 72 + 32 + lr] = __float2bfloat16(p2);
            myP[r * 72 + 48 + lr] = __float2bfloat16(p3);
            float sum = p0 + p1 + p2 + p3;
            sum += __shfl_xor(sum, 1);
            sum += __shfl_xor(sum, 2);
            sum += __shfl_xor(sum, 4);
            sum += __shfl_xor(sum, 8);
            l_r[j] = l_r[j] * rs[j] + sum;
            oacc[0][j] *= rs[j]; oacc[1][j] *= rs[j];
            oacc[2][j] *= rs[j]; oacc[3][j] *= rs[j];
        }

        #pragma unroll
        for (int kk = 0; kk < 2; ++kk) {
            bf16x8 pfrag = *(const bf16x8*)&myP[lr * 72 + kk * 32 + lg * 8];
            #pragma unroll
            for (int ct = 0; ct < 4; ++ct) {
                bf16x8 vfrag = *(const bf16x8*)&Vlds[(ct * 16 + lr) * 72 + kk * 32 + lg * 8];
                oacc[ct] = __builtin_amdgcn_mfma_f32_16x16x32_bf16(pfrag, vfrag, oacc[ct], 0, 0, 0);
            }
        }
        __syncthreads();
    }

    #pragma unroll
    for (int j = 0; j < 4; ++j) {
        const float invl = 1.0f / l_r[j];
        const int q = qtile * 64 + wave * 16 + lg * 4 + j;
        float* op = out + ((long)b * SEQ + q) * 1024 + h * 64;
        op[ 0 + lr] = oacc[0][j] * invl;
        op[16 + lr] = oacc[1][j] * invl;
        op[32 + lr] = oacc[2][j] * invl;
        op[48 + lr] = oacc[3][j] * invl;
    }
}

extern "C" void kernel_launch(void* const* d_in, const int* in_sizes, int n_in,
                              void* d_out, int out_size, void* d_ws, size_t ws_size,
                              hipStream_t stream) {
    const float* qf    = (const float*)d_in[0];
    const float* kf    = (const float*)d_in[1];
    const float* qc    = (const float*)d_in[2];
    const float* kc    = (const float*)d_in[3];
    const float* vv    = (const float*)d_in[4];
    const float* alpha = (const float*)d_in[5];
    float* out = (float*)d_out;

    const int B = 2;
    if (ws_size >= KP_BYTES + VT_BYTES) {
        char* kp = (char*)d_ws;
        char* vt = (char*)d_ws + KP_BYTES;
        pack_kv<<<2 * B * NHEADS * NT, 256, 0, stream>>>(kf, kc, vv, kp, vt);
        stfa_v11<<<B * NHEADS * (SEQ / QBLK), 256, 0, stream>>>(qf, qc, alpha, kp, vt, out);
    } else {
        stfa_v1<<<B * NHEADS * (SEQ / 64), 256, 0, stream>>>(qf, kf, qc, kc, vv, alpha, out);
    }
}